// Round 1
// baseline (1037.143 us; speedup 1.0000x reference)
//
#include <hip/hip_runtime.h>
#include <cstddef>

#define NB 8
#define NH 16
#define NS 512
#define NDH 64
#define NHID 1024

#define QKV_ELEMS (NB*NH*NS*NDH)            /* 4194304 */
#define ATTN_ELEMS ((size_t)NB*NH*(size_t)NS*NS) /* 33554432 */

// ---------------------------------------------------------------------------
// K0: per-sample valid lengths (first zero index, else S). lens[0..7]=q, [8..15]=k
__global__ void lens_kernel(const int* __restrict__ pq, const int* __restrict__ pk,
                            int* __restrict__ lens) {
    int bi = blockIdx.x;                       // 0..15
    const int* v = (bi < NB) ? pq : pk;
    int b = bi & (NB - 1);
    int lane = threadIdx.x;                    // one wave (64)
    int local = NS;
#pragma unroll
    for (int p = 0; p < NS / 64; ++p) {
        int idx = p * 64 + lane;
        if (v[b * NS + idx] == 0 && idx < local) local = idx;
    }
#pragma unroll
    for (int m = 32; m >= 1; m >>= 1) {
        int o = __shfl_xor(local, m, 64);
        local = min(local, o);
    }
    if (lane == 0) lens[bi] = local;
}

// ---------------------------------------------------------------------------
// K1: 4 projection GEMMs. A[m, c] = src[b, c/64, s, c%64] (m=b*S+s), W row-major.
// dst layout [B,H,S,DH]. 128x128 block tile, BK=16, 256 thr, 8x8 per thread.
__global__ __launch_bounds__(256) void proj_kernel(
    const float* __restrict__ hl, const float* __restrict__ hc,
    const float* __restrict__ Wq, const float* __restrict__ bq,
    const float* __restrict__ Wk, const float* __restrict__ bk,
    const float* __restrict__ Wv1, const float* __restrict__ bv1,
    const float* __restrict__ Wv, const float* __restrict__ bv,
    float* __restrict__ oq, float* __restrict__ ok,
    float* __restrict__ ov1, float* __restrict__ ovt) {
    __shared__ float As[16][132];
    __shared__ float Bs[16][132];
    const float* src; const float* W; const float* bias; float* dst;
    switch (blockIdx.z) {
        case 0: src = hl; W = Wq;  bias = bq;  dst = oq;  break;
        case 1: src = hc; W = Wk;  bias = bk;  dst = ok;  break;
        case 2: src = hl; W = Wv1; bias = bv1; dst = ov1; break;
        default: src = hc; W = Wv;  bias = bv;  dst = ovt; break;
    }
    int t = threadIdx.x;
    int tx = t & 15, ty = t >> 4;
    int m0 = blockIdx.y * 128;
    int n0 = blockIdx.x * 128;
    float acc[8][8];
#pragma unroll
    for (int i = 0; i < 8; ++i)
#pragma unroll
        for (int j = 0; j < 8; ++j) acc[i][j] = 0.f;

    for (int k0 = 0; k0 < NHID; k0 += 16) {
#pragma unroll
        for (int p = 0; p < 8; ++p) {              // A tile: 128 rows x 16 k
            int e = p * 256 + t;
            int kk = e & 15, mm = e >> 4;
            int m = m0 + mm;
            int b = m >> 9, s = m & (NS - 1);
            int c = k0 + kk;
            As[kk][mm] = src[(((size_t)b * NH + (c >> 6)) * NS + s) * NDH + (c & 63)];
        }
#pragma unroll
        for (int p = 0; p < 8; ++p) {              // B tile: 16 k x 128 n
            int e = p * 256 + t;
            int nn = e & 127, kk = e >> 7;
            Bs[kk][nn] = W[(size_t)(k0 + kk) * NHID + n0 + nn];
        }
        __syncthreads();
#pragma unroll
        for (int kk = 0; kk < 16; ++kk) {
            float a[8], bb[8];
            *(float4*)&a[0]  = *(const float4*)&As[kk][ty * 8];
            *(float4*)&a[4]  = *(const float4*)&As[kk][ty * 8 + 4];
            *(float4*)&bb[0] = *(const float4*)&Bs[kk][tx * 8];
            *(float4*)&bb[4] = *(const float4*)&Bs[kk][tx * 8 + 4];
#pragma unroll
            for (int i = 0; i < 8; ++i)
#pragma unroll
                for (int j = 0; j < 8; ++j) acc[i][j] += a[i] * bb[j];
        }
        __syncthreads();
    }
#pragma unroll
    for (int i = 0; i < 8; ++i) {
        int m = m0 + ty * 8 + i;
        int b = m >> 9, s = m & (NS - 1);
#pragma unroll
        for (int jj = 0; jj < 2; ++jj) {
            int n = n0 + tx * 8 + jj * 4;
            int h = n >> 6, d = n & 63;
            float4 o;
            o.x = acc[i][jj * 4 + 0] + bias[n + 0];
            o.y = acc[i][jj * 4 + 1] + bias[n + 1];
            o.z = acc[i][jj * 4 + 2] + bias[n + 2];
            o.w = acc[i][jj * 4 + 3] + bias[n + 3];
            *(float4*)&dst[(((size_t)b * NH + h) * NS + s) * NDH + d] = o;
        }
    }
}

// ---------------------------------------------------------------------------
// K2: scores_t[bh, ki, qi] = dot(k[bh,ki,:], q[bh,qi,:]) / 8   (K @ Q^T)
__global__ __launch_bounds__(256) void scores_kernel(
    const float* __restrict__ q, const float* __restrict__ k,
    float* __restrict__ scores_t) {
    __shared__ float Ks[64][68];
    __shared__ float Qs[64][68];
    int bh = blockIdx.z;
    int ki0 = blockIdx.x * 64;
    int qi0 = blockIdx.y * 64;
    const float* qb = q + (size_t)bh * NS * NDH;
    const float* kb = k + (size_t)bh * NS * NDH;
    int t = threadIdx.x;
#pragma unroll
    for (int p = 0; p < 4; ++p) {                  // 64x64 fp32 tiles, float4 loads
        int f = p * 256 + t;
        int r = f >> 4, c4 = (f & 15) * 4;
        *(float4*)&Ks[r][c4] = *(const float4*)&kb[(size_t)(ki0 + r) * NDH + c4];
        *(float4*)&Qs[r][c4] = *(const float4*)&qb[(size_t)(qi0 + r) * NDH + c4];
    }
    __syncthreads();
    int tx = t & 15, ty = t >> 4;
    float acc[4][4];
#pragma unroll
    for (int i = 0; i < 4; ++i)
#pragma unroll
        for (int j = 0; j < 4; ++j) acc[i][j] = 0.f;
#pragma unroll
    for (int d4 = 0; d4 < NDH; d4 += 4) {
        float a[4][4], bqv[4][4];
#pragma unroll
        for (int i = 0; i < 4; ++i)
            *(float4*)&a[i][0] = *(const float4*)&Ks[ty * 4 + i][d4];
#pragma unroll
        for (int j = 0; j < 4; ++j)
            *(float4*)&bqv[j][0] = *(const float4*)&Qs[tx * 4 + j][d4];
#pragma unroll
        for (int dd = 0; dd < 4; ++dd)
#pragma unroll
            for (int i = 0; i < 4; ++i)
#pragma unroll
                for (int j = 0; j < 4; ++j) acc[i][j] += a[i][dd] * bqv[j][dd];
    }
#pragma unroll
    for (int i = 0; i < 4; ++i) {
        float4 o;
        o.x = acc[i][0] * 0.125f;
        o.y = acc[i][1] * 0.125f;
        o.z = acc[i][2] * 0.125f;
        o.w = acc[i][3] * 0.125f;
        *(float4*)&scores_t[((size_t)bh * NS + ki0 + ty * 4 + i) * NS + qi0 + tx * 4] = o;
    }
}

// ---------------------------------------------------------------------------
// K3: masked softmax over last axis of scores_t -> attention_values.
// Row (b,h,ki): fully masked if ki>=len_q[b] -> zeros. Cols qi>=len_k[b] -> 0.
__global__ __launch_bounds__(256) void softmax_kernel(
    const float* __restrict__ scores_t, const int* __restrict__ lens,
    float* __restrict__ attn) {
    int wid = threadIdx.x >> 6, lane = threadIdx.x & 63;
    int row = blockIdx.x * 4 + wid;                // 0..65535 = bh*S + ki
    int b = row >> 13;                             // H*S = 8192
    int ki = row & (NS - 1);
    int lq = lens[b], lk = lens[NB + b];
    float* orow = attn + (size_t)row * NS;
    if (ki >= lq) {
        float4 z = make_float4(0.f, 0.f, 0.f, 0.f);
        *(float4*)&orow[lane * 8] = z;
        *(float4*)&orow[lane * 8 + 4] = z;
        return;
    }
    const float* srow = scores_t + (size_t)row * NS;
    float v[8];
    *(float4*)&v[0] = *(const float4*)&srow[lane * 8];
    *(float4*)&v[4] = *(const float4*)&srow[lane * 8 + 4];
    int base = lane * 8;
    float mx = -3.0e38f;
#pragma unroll
    for (int u = 0; u < 8; ++u)
        if (base + u < lk) mx = fmaxf(mx, v[u]);
#pragma unroll
    for (int m = 32; m >= 1; m >>= 1) mx = fmaxf(mx, __shfl_xor(mx, m, 64));
    float e[8]; float sum = 0.f;
#pragma unroll
    for (int u = 0; u < 8; ++u) {
        e[u] = (base + u < lk) ? __expf(v[u] - mx) : 0.f;
        sum += e[u];
    }
#pragma unroll
    for (int m = 32; m >= 1; m >>= 1) sum += __shfl_xor(sum, m, 64);
    float inv = 1.f / sum;
    float4 o0 = make_float4(e[0] * inv, e[1] * inv, e[2] * inv, e[3] * inv);
    float4 o1 = make_float4(e[4] * inv, e[5] * inv, e[6] * inv, e[7] * inv);
    *(float4*)&orow[lane * 8] = o0;
    *(float4*)&orow[lane * 8 + 4] = o1;
}

// ---------------------------------------------------------------------------
// K4: context[bh, ki, d] = sum_qi attn[bh, ki, qi] * v1[bh, qi, d]
__global__ __launch_bounds__(256) void context_kernel(
    const float* __restrict__ attn, const float* __restrict__ v1,
    float* __restrict__ ctx) {
    __shared__ float As[64][33];
    __shared__ float Vs[32][68];
    int bh = blockIdx.y;
    int ki0 = blockIdx.x * 64;
    const float* ab = attn + ((size_t)bh * NS + ki0) * NS;
    const float* vb = v1 + (size_t)bh * NS * NDH;
    int t = threadIdx.x;
    int tx = t & 15, ty = t >> 4;
    float acc[4][4];
#pragma unroll
    for (int i = 0; i < 4; ++i)
#pragma unroll
        for (int j = 0; j < 4; ++j) acc[i][j] = 0.f;

    for (int qi0 = 0; qi0 < NS; qi0 += 32) {
#pragma unroll
        for (int p = 0; p < 8; ++p) {              // attn tile 64 x 32
            int e = p * 256 + t;
            int c = e & 31, r = e >> 5;
            As[r][c] = ab[(size_t)r * NS + qi0 + c];
        }
#pragma unroll
        for (int p = 0; p < 2; ++p) {              // v1 tile 32 x 64
            int f = p * 256 + t;
            int r = f >> 4, c4 = (f & 15) * 4;
            *(float4*)&Vs[r][c4] = *(const float4*)&vb[(size_t)(qi0 + r) * NDH + c4];
        }
        __syncthreads();
#pragma unroll
        for (int kk = 0; kk < 32; ++kk) {
            float a0 = As[ty * 4 + 0][kk];
            float a1 = As[ty * 4 + 1][kk];
            float a2 = As[ty * 4 + 2][kk];
            float a3 = As[ty * 4 + 3][kk];
            float4 bv4 = *(const float4*)&Vs[kk][tx * 4];
            acc[0][0] += a0 * bv4.x; acc[0][1] += a0 * bv4.y; acc[0][2] += a0 * bv4.z; acc[0][3] += a0 * bv4.w;
            acc[1][0] += a1 * bv4.x; acc[1][1] += a1 * bv4.y; acc[1][2] += a1 * bv4.z; acc[1][3] += a1 * bv4.w;
            acc[2][0] += a2 * bv4.x; acc[2][1] += a2 * bv4.y; acc[2][2] += a2 * bv4.z; acc[2][3] += a2 * bv4.w;
            acc[3][0] += a3 * bv4.x; acc[3][1] += a3 * bv4.y; acc[3][2] += a3 * bv4.z; acc[3][3] += a3 * bv4.w;
        }
        __syncthreads();
    }
#pragma unroll
    for (int i = 0; i < 4; ++i) {
        float4 o = make_float4(acc[i][0], acc[i][1], acc[i][2], acc[i][3]);
        *(float4*)&ctx[((size_t)bh * NS + ki0 + ty * 4 + i) * NDH + tx * 4] = o;
    }
}

// ---------------------------------------------------------------------------
// K5: context2 = concat([ctx, vt], -1) @ W_cat + b_cat. io holds vt on entry,
// context2 on exit (in-place per-row: reads complete before epilogue writes).
__global__ __launch_bounds__(256) void cat_kernel(
    const float* __restrict__ ctx, const float* __restrict__ Wcat,
    const float* __restrict__ bcat, float* __restrict__ io) {
    __shared__ float As[16][68];
    __shared__ float Bs[16][68];
    int t = threadIdx.x;
    int tx = t & 15, ty = t >> 4;
    int row0 = blockIdx.x * 64;
    float acc[4][4];
#pragma unroll
    for (int i = 0; i < 4; ++i)
#pragma unroll
        for (int j = 0; j < 4; ++j) acc[i][j] = 0.f;

    for (int k0 = 0; k0 < 2 * NDH; k0 += 16) {
#pragma unroll
        for (int p = 0; p < 4; ++p) {              // A tile 64 rows x 16 k (concat)
            int e = p * 256 + t;
            int kk = e & 15, mm = e >> 4;
            int c = k0 + kk;
            float val = (c < NDH) ? ctx[(size_t)(row0 + mm) * NDH + c]
                                  : io[(size_t)(row0 + mm) * NDH + (c - NDH)];
            As[kk][mm] = val;
        }
#pragma unroll
        for (int p = 0; p < 4; ++p) {              // B tile 16 x 64
            int e = p * 256 + t;
            int nn = e & 63, kk = e >> 6;
            Bs[kk][nn] = Wcat[(size_t)(k0 + kk) * NDH + nn];
        }
        __syncthreads();
#pragma unroll
        for (int kk = 0; kk < 16; ++kk) {
            float a[4], bb[4];
            *(float4*)&a[0]  = *(const float4*)&As[kk][ty * 4];
            *(float4*)&bb[0] = *(const float4*)&Bs[kk][tx * 4];
#pragma unroll
            for (int i = 0; i < 4; ++i)
#pragma unroll
                for (int j = 0; j < 4; ++j) acc[i][j] += a[i] * bb[j];
        }
        __syncthreads();
    }
#pragma unroll
    for (int i = 0; i < 4; ++i) {
        int n = tx * 4;
        float4 o;
        o.x = acc[i][0] + bcat[n + 0];
        o.y = acc[i][1] + bcat[n + 1];
        o.z = acc[i][2] + bcat[n + 2];
        o.w = acc[i][3] + bcat[n + 3];
        *(float4*)&io[(size_t)(row0 + ty * 4 + i) * NDH + n] = o;
    }
}

// ---------------------------------------------------------------------------
extern "C" void kernel_launch(void* const* d_in, const int* in_sizes, int n_in,
                              void* d_out, int out_size, void* d_ws, size_t ws_size,
                              hipStream_t stream) {
    (void)in_sizes; (void)n_in; (void)out_size; (void)ws_size;
    const int*   pq   = (const int*)d_in[0];
    const int*   pk   = (const int*)d_in[1];
    const float* hl   = (const float*)d_in[6];
    const float* hc   = (const float*)d_in[7];
    const float* Wv1  = (const float*)d_in[11];
    const float* bv1  = (const float*)d_in[12];
    const float* Wv   = (const float*)d_in[13];
    const float* bv   = (const float*)d_in[14];
    const float* Wq   = (const float*)d_in[15];
    const float* bq   = (const float*)d_in[16];
    const float* Wk   = (const float*)d_in[17];
    const float* bk   = (const float*)d_in[18];
    const float* Wcat = (const float*)d_in[19];
    const float* bcat = (const float*)d_in[20];

    float* out_attn   = (float*)d_out;                       // [B,H,S,S]
    float* out_scores = out_attn + ATTN_ELEMS;               // [B,H,S,S]
    float* out_ctx2   = out_attn + 2 * ATTN_ELEMS;           // [B,H,S,DH]
    float* out_ctx    = out_ctx2 + QKV_ELEMS;                // [B,H,S,DH]

    // q,k parked in the (not-yet-written) attention output region; v1/vt parked
    // in the context/context2 output regions. Workspace: 16 MB ctx temp + lens.
    float* q   = out_attn;
    float* k   = out_attn + QKV_ELEMS;
    float* ctx_tmp = (float*)d_ws;
    int*   lens = (int*)((char*)d_ws + (size_t)QKV_ELEMS * sizeof(float));

    lens_kernel<<<16, 64, 0, stream>>>(pq, pk, lens);
    proj_kernel<<<dim3(NHID / 128, (NB * NS) / 128, 4), 256, 0, stream>>>(
        hl, hc, Wq, bq, Wk, bk, Wv1, bv1, Wv, bv,
        q, k, out_ctx /*v1 temp*/, out_ctx2 /*vt temp*/);
    scores_kernel<<<dim3(NS / 64, NS / 64, NB * NH), 256, 0, stream>>>(q, k, out_scores);
    softmax_kernel<<<(NB * NH * NS) / 4, 256, 0, stream>>>(out_scores, lens, out_attn);
    context_kernel<<<dim3(NS / 64, NB * NH), 256, 0, stream>>>(out_attn, out_ctx /*v1*/, ctx_tmp);
    hipMemcpyAsync(out_ctx, ctx_tmp, (size_t)QKV_ELEMS * sizeof(float),
                   hipMemcpyDeviceToDevice, stream);
    cat_kernel<<<(NB * NH * NS) / 64, 256, 0, stream>>>(ctx_tmp, Wcat, bcat, out_ctx2);
}

// Round 2
// 546.259 us; speedup vs baseline: 1.8986x; 1.8986x over previous
//
#include <hip/hip_runtime.h>
#include <cstddef>

#define NB 8
#define NH 16
#define NS 512
#define NDH 64
#define NHID 1024
#define NBH (NB*NH)

#define QKV_ELEMS (NB*NH*NS*NDH)                 /* 4194304 */
#define ATTN_ELEMS ((size_t)NB*NH*(size_t)NS*NS) /* 33554432 */

typedef __bf16 bf16;
typedef __attribute__((ext_vector_type(8))) __bf16 bf16x8;
typedef __attribute__((ext_vector_type(4))) __bf16 bf16x4;
typedef __attribute__((ext_vector_type(4))) float f32x4;

// XOR swizzle in SHORT units: byte ^= ((row&7)<<4)  (T2/G4 — spreads 8 rows
// of a 64/128B-stride tile across all 32 banks; 2-way residual = free)
__device__ __forceinline__ int swz(int idx, int row) { return idx ^ ((row & 7) << 3); }

// ---------------------------------------------------------------------------
// K0: per-sample valid lengths (first zero index, else S). lens[0..7]=q, [8..15]=k
__global__ void lens_kernel(const int* __restrict__ pq, const int* __restrict__ pk,
                            int* __restrict__ lens) {
    int bi = blockIdx.x;
    const int* v = (bi < NB) ? pq : pk;
    int b = bi & (NB - 1);
    int lane = threadIdx.x;
    int local = NS;
#pragma unroll
    for (int p = 0; p < NS / 64; ++p) {
        int idx = p * 64 + lane;
        if (v[b * NS + idx] == 0 && idx < local) local = idx;
    }
#pragma unroll
    for (int m = 32; m >= 1; m >>= 1) {
        int o = __shfl_xor(local, m, 64);
        local = min(local, o);
    }
    if (lane == 0) lens[bi] = local;
}

// ---------------------------------------------------------------------------
// K1: 4 projection GEMMs, bf16 MFMA. A[m,c] = src[b, c/64, s, c%64], W row-major.
// 128x128 tile, BK=32, 4 waves (each 64x64 via 4x4 frags of 16x16x32).
// Outputs bf16 in [bh, s, d] layout.
__global__ __launch_bounds__(256) void proj_kernel(
    const float* __restrict__ hl, const float* __restrict__ hc,
    const float* __restrict__ Wq, const float* __restrict__ bq,
    const float* __restrict__ Wk, const float* __restrict__ bk,
    const float* __restrict__ Wv1, const float* __restrict__ bv1,
    const float* __restrict__ Wv, const float* __restrict__ bv,
    bf16* __restrict__ oq, bf16* __restrict__ ok,
    bf16* __restrict__ ov1, bf16* __restrict__ ovt) {
    __shared__ bf16 As[128 * 32];   // [m][k]
    __shared__ bf16 Bs[128 * 32];   // [n][k]
    const float* src; const float* W; const float* bias; bf16* dst;
    switch (blockIdx.z) {
        case 0: src = hl; W = Wq;  bias = bq;  dst = oq;  break;
        case 1: src = hc; W = Wk;  bias = bk;  dst = ok;  break;
        case 2: src = hl; W = Wv1; bias = bv1; dst = ov1; break;
        default: src = hc; W = Wv;  bias = bv;  dst = ovt; break;
    }
    int t = threadIdx.x;
    int lane = t & 63, w = t >> 6;
    int wm = w & 1, wn = w >> 1;
    int m0 = blockIdx.y * 128, n0 = blockIdx.x * 128;
    f32x4 acc[4][4];
#pragma unroll
    for (int i = 0; i < 4; ++i)
#pragma unroll
        for (int j = 0; j < 4; ++j) acc[i][j] = (f32x4){0.f, 0.f, 0.f, 0.f};

    for (int k0 = 0; k0 < NHID; k0 += 32) {
#pragma unroll
        for (int p = 0; p < 4; ++p) {          // A tile 128 rows x 32 k
            int f = p * 256 + t;
            int row = f >> 3, c4 = (f & 7) * 4;
            int m = m0 + row, b = m >> 9, s = m & (NS - 1);
            int c = k0 + c4;
            float4 v = *(const float4*)&src[(((size_t)b * NH + (c >> 6)) * NS + s) * NDH + (c & 63)];
            bf16x4 h;
            h[0] = (bf16)v.x; h[1] = (bf16)v.y; h[2] = (bf16)v.z; h[3] = (bf16)v.w;
            *(bf16x4*)&As[swz(row * 32 + c4, row)] = h;
        }
#pragma unroll
        for (int p = 0; p < 4; ++p) {          // B tile 32 k x 128 n -> [n][k]
            int f = p * 256 + t;
            int n = f & 127, kk = (f >> 7) * 4;
            const float* wp = &W[(size_t)(k0 + kk) * NHID + n0 + n];
            bf16x4 h;
            h[0] = (bf16)wp[0]; h[1] = (bf16)wp[NHID];
            h[2] = (bf16)wp[2 * NHID]; h[3] = (bf16)wp[3 * NHID];
            *(bf16x4*)&Bs[swz(n * 32 + kk, n)] = h;
        }
        __syncthreads();
        int kb8 = (lane >> 4) * 8;
        bf16x8 a[4], bfr[4];
#pragma unroll
        for (int i = 0; i < 4; ++i) {
            int row = wm * 64 + i * 16 + (lane & 15);
            a[i] = *(const bf16x8*)&As[swz(row * 32 + kb8, row)];
        }
#pragma unroll
        for (int j = 0; j < 4; ++j) {
            int nr = wn * 64 + j * 16 + (lane & 15);
            bfr[j] = *(const bf16x8*)&Bs[swz(nr * 32 + kb8, nr)];
        }
#pragma unroll
        for (int i = 0; i < 4; ++i)
#pragma unroll
            for (int j = 0; j < 4; ++j)
                acc[i][j] = __builtin_amdgcn_mfma_f32_16x16x32_bf16(a[i], bfr[j], acc[i][j], 0, 0, 0);
        __syncthreads();
    }
    float bs[4];
#pragma unroll
    for (int j = 0; j < 4; ++j) bs[j] = bias[n0 + wn * 64 + j * 16 + (lane & 15)];
#pragma unroll
    for (int i = 0; i < 4; ++i)
#pragma unroll
        for (int r = 0; r < 4; ++r) {
            int m = m0 + wm * 64 + i * 16 + (lane >> 4) * 4 + r;
            int b = m >> 9, s = m & (NS - 1);
#pragma unroll
            for (int j = 0; j < 4; ++j) {
                int n = n0 + wn * 64 + j * 16 + (lane & 15);
                dst[(((size_t)b * NH + (n >> 6)) * NS + s) * NDH + (n & 63)] =
                    (bf16)(acc[i][j][r] + bs[j]);
            }
        }
}

// ---------------------------------------------------------------------------
// K2: fused scores + masked softmax. Per block: 64 ki x 512 qi for one bh.
// scores_t (fp32, unmasked, /8) and attn (fp32, masked softmax) both written.
__global__ __launch_bounds__(256) void attn_kernel(
    const bf16* __restrict__ qb, const bf16* __restrict__ kb,
    const int* __restrict__ lens,
    float* __restrict__ scores, float* __restrict__ attn) {
    __shared__ bf16 Ks[64 * 64];
    __shared__ float redm[4][64];
    __shared__ float reds[4][64];
    int bh = blockIdx.y, ki0 = blockIdx.x * 64;
    int b = bh >> 4;
    int t = threadIdx.x, lane = t & 63, w = t >> 6;
    int lq = lens[b], lk = lens[NB + b];
    const bf16* kbb = kb + ((size_t)bh * NS + ki0) * NDH;
    const bf16* qbb = qb + (size_t)bh * NS * NDH;
#pragma unroll
    for (int p = 0; p < 2; ++p) {              // K tile 64x64
        int f = p * 256 + t;
        int row = f >> 3, d8 = (f & 7) * 8;
        bf16x8 v = *(const bf16x8*)&kbb[(size_t)row * NDH + d8];
        *(bf16x8*)&Ks[swz(row * 64 + d8, row)] = v;
    }
    __syncthreads();
    f32x4 acc[4][8];
#pragma unroll
    for (int i = 0; i < 4; ++i)
#pragma unroll
        for (int j = 0; j < 8; ++j) acc[i][j] = (f32x4){0.f, 0.f, 0.f, 0.f};
#pragma unroll
    for (int ds = 0; ds < 2; ++ds) {
        int kofs = ds * 32 + (lane >> 4) * 8;
        bf16x8 a[4];
#pragma unroll
        for (int i = 0; i < 4; ++i) {
            int row = i * 16 + (lane & 15);
            a[i] = *(const bf16x8*)&Ks[swz(row * 64 + kofs, row)];
        }
#pragma unroll
        for (int j = 0; j < 8; ++j) {
            int qi = w * 128 + j * 16 + (lane & 15);
            bf16x8 bq8 = *(const bf16x8*)&qbb[(size_t)qi * NDH + kofs];
#pragma unroll
            for (int i = 0; i < 4; ++i)
                acc[i][j] = __builtin_amdgcn_mfma_f32_16x16x32_bf16(a[i], bq8, acc[i][j], 0, 0, 0);
        }
    }
    int g = lane >> 4, c = lane & 15;
    float pmax[4][4];
#pragma unroll
    for (int i = 0; i < 4; ++i)
#pragma unroll
        for (int r = 0; r < 4; ++r) pmax[i][r] = -3.0e38f;
#pragma unroll
    for (int i = 0; i < 4; ++i)
#pragma unroll
        for (int j = 0; j < 8; ++j) {
            int qi = w * 128 + j * 16 + c;
            bool colv = qi < lk;
#pragma unroll
            for (int r = 0; r < 4; ++r) {
                float s = acc[i][j][r] * 0.125f;
                acc[i][j][r] = s;
                scores[((size_t)bh * NS + ki0 + i * 16 + g * 4 + r) * NS + qi] = s;
                if (colv) pmax[i][r] = fmaxf(pmax[i][r], s);
            }
        }
#pragma unroll
    for (int msk = 8; msk >= 1; msk >>= 1)
#pragma unroll
        for (int i = 0; i < 4; ++i)
#pragma unroll
            for (int r = 0; r < 4; ++r)
                pmax[i][r] = fmaxf(pmax[i][r], __shfl_xor(pmax[i][r], msk, 64));
    if (c == 0)
#pragma unroll
        for (int i = 0; i < 4; ++i)
#pragma unroll
            for (int r = 0; r < 4; ++r) redm[w][i * 16 + g * 4 + r] = pmax[i][r];
    __syncthreads();
    float rmax[4][4];
#pragma unroll
    for (int i = 0; i < 4; ++i)
#pragma unroll
        for (int r = 0; r < 4; ++r) {
            int row = i * 16 + g * 4 + r;
            rmax[i][r] = fmaxf(fmaxf(redm[0][row], redm[1][row]),
                               fmaxf(redm[2][row], redm[3][row]));
        }
    float psum[4][4];
#pragma unroll
    for (int i = 0; i < 4; ++i)
#pragma unroll
        for (int r = 0; r < 4; ++r) psum[i][r] = 0.f;
#pragma unroll
    for (int i = 0; i < 4; ++i)
#pragma unroll
        for (int j = 0; j < 8; ++j) {
            int qi = w * 128 + j * 16 + c;
            bool colv = qi < lk;
#pragma unroll
            for (int r = 0; r < 4; ++r) {
                float e = colv ? __expf(acc[i][j][r] - rmax[i][r]) : 0.f;
                acc[i][j][r] = e;
                psum[i][r] += e;
            }
        }
#pragma unroll
    for (int msk = 8; msk >= 1; msk >>= 1)
#pragma unroll
        for (int i = 0; i < 4; ++i)
#pragma unroll
            for (int r = 0; r < 4; ++r)
                psum[i][r] += __shfl_xor(psum[i][r], msk, 64);
    if (c == 0)
#pragma unroll
        for (int i = 0; i < 4; ++i)
#pragma unroll
            for (int r = 0; r < 4; ++r) reds[w][i * 16 + g * 4 + r] = psum[i][r];
    __syncthreads();
#pragma unroll
    for (int i = 0; i < 4; ++i)
#pragma unroll
        for (int r = 0; r < 4; ++r) {
            int row = i * 16 + g * 4 + r;
            float rs = reds[0][row] + reds[1][row] + reds[2][row] + reds[3][row];
            float inv = (rs > 0.f) ? 1.f / rs : 0.f;
            bool rowv = (ki0 + row) < lq;
#pragma unroll
            for (int j = 0; j < 8; ++j) {
                int qi = w * 128 + j * 16 + c;
                float v = rowv ? acc[i][j][r] * inv : 0.f;
                attn[((size_t)bh * NS + ki0 + row) * NS + qi] = v;
            }
        }
}

// ---------------------------------------------------------------------------
// K3: context = attn @ v1 (bf16 MFMA; attn cvt'd on the fly, v1 transposed into LDS)
__global__ __launch_bounds__(256) void context_kernel(
    const float* __restrict__ attn, const bf16* __restrict__ v1,
    float* __restrict__ ctx) {
    __shared__ bf16 Ash[64 * 64];   // [ki][qi]
    __shared__ bf16 Vs[64 * 64];    // [d][qi]
    int bh = blockIdx.y, ki0 = blockIdx.x * 64;
    int t = threadIdx.x, lane = t & 63, w = t >> 6;
    const float* ab = attn + ((size_t)bh * NS + ki0) * NS;
    const bf16* vb = v1 + (size_t)bh * NS * NDH;
    f32x4 acc[4];
#pragma unroll
    for (int j = 0; j < 4; ++j) acc[j] = (f32x4){0.f, 0.f, 0.f, 0.f};

    for (int q0 = 0; q0 < NS; q0 += 64) {
#pragma unroll
        for (int p = 0; p < 4; ++p) {          // attn 64x64 fp32 -> bf16
            int f = p * 256 + t;
            int row = f >> 4, c4 = (f & 15) * 4;
            float4 v = *(const float4*)&ab[(size_t)row * NS + q0 + c4];
            bf16x4 h;
            h[0] = (bf16)v.x; h[1] = (bf16)v.y; h[2] = (bf16)v.z; h[3] = (bf16)v.w;
            *(bf16x4*)&Ash[swz(row * 64 + c4, row)] = h;
        }
#pragma unroll
        for (int p = 0; p < 2; ++p) {          // v1 64x64 transposed -> [d][qi]
            int f = p * 256 + t;
            int qr = f >> 3, d8 = (f & 7) * 8;
            bf16x8 v = *(const bf16x8*)&vb[(size_t)(q0 + qr) * NDH + d8];
#pragma unroll
            for (int e = 0; e < 8; ++e) {
                int d = d8 + e;
                Vs[swz(d * 64 + qr, d)] = v[e];
            }
        }
        __syncthreads();
#pragma unroll
        for (int kk = 0; kk < 2; ++kk) {
            int kofs = kk * 32 + (lane >> 4) * 8;
            int arow = w * 16 + (lane & 15);
            bf16x8 a = *(const bf16x8*)&Ash[swz(arow * 64 + kofs, arow)];
#pragma unroll
            for (int j = 0; j < 4; ++j) {
                int d = j * 16 + (lane & 15);
                bf16x8 bv8 = *(const bf16x8*)&Vs[swz(d * 64 + kofs, d)];
                acc[j] = __builtin_amdgcn_mfma_f32_16x16x32_bf16(a, bv8, acc[j], 0, 0, 0);
            }
        }
        __syncthreads();
    }
    int g = lane >> 4, c = lane & 15;
#pragma unroll
    for (int j = 0; j < 4; ++j)
#pragma unroll
        for (int r = 0; r < 4; ++r) {
            int ki = ki0 + w * 16 + g * 4 + r;
            ctx[((size_t)bh * NS + ki) * NDH + j * 16 + c] = acc[j][r];
        }
}

// ---------------------------------------------------------------------------
// K4: context2 = concat([ctx, vt], -1) @ W_cat + b_cat  (fp32, small)
__global__ __launch_bounds__(256) void cat_kernel(
    const float* __restrict__ ctx, const bf16* __restrict__ vt,
    const float* __restrict__ Wcat, const float* __restrict__ bcat,
    float* __restrict__ out) {
    __shared__ float As[16][68];
    __shared__ float Bs[16][68];
    int t = threadIdx.x;
    int tx = t & 15, ty = t >> 4;
    int row0 = blockIdx.x * 64;
    float acc[4][4];
#pragma unroll
    for (int i = 0; i < 4; ++i)
#pragma unroll
        for (int j = 0; j < 4; ++j) acc[i][j] = 0.f;

    for (int k0 = 0; k0 < 2 * NDH; k0 += 16) {
#pragma unroll
        for (int p = 0; p < 4; ++p) {
            int e = p * 256 + t;
            int kk = e & 15, mm = e >> 4;
            int cidx = k0 + kk;
            float val = (cidx < NDH) ? ctx[(size_t)(row0 + mm) * NDH + cidx]
                                     : (float)vt[(size_t)(row0 + mm) * NDH + (cidx - NDH)];
            As[kk][mm] = val;
        }
#pragma unroll
        for (int p = 0; p < 4; ++p) {
            int e = p * 256 + t;
            int nn = e & 63, kk = e >> 6;
            Bs[kk][nn] = Wcat[(size_t)(k0 + kk) * NDH + nn];
        }
        __syncthreads();
#pragma unroll
        for (int kk = 0; kk < 16; ++kk) {
            float a[4], bb[4];
            *(float4*)&a[0]  = *(const float4*)&As[kk][ty * 4];
            *(float4*)&bb[0] = *(const float4*)&Bs[kk][tx * 4];
#pragma unroll
            for (int i = 0; i < 4; ++i)
#pragma unroll
                for (int j = 0; j < 4; ++j) acc[i][j] += a[i] * bb[j];
        }
        __syncthreads();
    }
#pragma unroll
    for (int i = 0; i < 4; ++i) {
        int n = tx * 4;
        float4 o;
        o.x = acc[i][0] + bcat[n + 0];
        o.y = acc[i][1] + bcat[n + 1];
        o.z = acc[i][2] + bcat[n + 2];
        o.w = acc[i][3] + bcat[n + 3];
        *(float4*)&out[(size_t)(row0 + ty * 4 + i) * NDH + n] = o;
    }
}

// ---------------------------------------------------------------------------
extern "C" void kernel_launch(void* const* d_in, const int* in_sizes, int n_in,
                              void* d_out, int out_size, void* d_ws, size_t ws_size,
                              hipStream_t stream) {
    (void)in_sizes; (void)n_in; (void)out_size; (void)ws_size;
    const int*   pq   = (const int*)d_in[0];
    const int*   pk   = (const int*)d_in[1];
    const float* hl   = (const float*)d_in[6];
    const float* hc   = (const float*)d_in[7];
    const float* Wv1  = (const float*)d_in[11];
    const float* bv1  = (const float*)d_in[12];
    const float* Wv   = (const float*)d_in[13];
    const float* bv   = (const float*)d_in[14];
    const float* Wq   = (const float*)d_in[15];
    const float* bq   = (const float*)d_in[16];
    const float* Wk   = (const float*)d_in[17];
    const float* bk   = (const float*)d_in[18];
    const float* Wcat = (const float*)d_in[19];
    const float* bcat = (const float*)d_in[20];

    float* out_attn   = (float*)d_out;             // [B,H,S,S]
    float* out_scores = out_attn + ATTN_ELEMS;     // [B,H,S,S]
    float* out_ctx2   = out_attn + 2 * ATTN_ELEMS; // [B,H,S,DH]
    float* out_ctx    = out_ctx2 + QKV_ELEMS;      // [B,H,S,DH]

    // bf16 intermediates: q,k in ws (dead before ctx_ws reuses the region);
    // v1,vt parked in the not-yet-final out_ctx region (fp32-sized = 2x bf16).
    bf16*  qb     = (bf16*)d_ws;
    bf16*  kbp    = qb + QKV_ELEMS;
    float* ctx_ws = (float*)d_ws;                  // reuses qb/kb region after attn
    int*   lens   = (int*)((char*)d_ws + (size_t)QKV_ELEMS * sizeof(float));
    bf16*  v1b    = (bf16*)out_ctx;
    bf16*  vtb    = v1b + QKV_ELEMS;

    lens_kernel<<<16, 64, 0, stream>>>(pq, pk, lens);
    proj_kernel<<<dim3(8, 32, 4), 256, 0, stream>>>(
        hl, hc, Wq, bq, Wk, bk, Wv1, bv1, Wv, bv, qb, kbp, v1b, vtb);
    attn_kernel<<<dim3(8, NBH), 256, 0, stream>>>(qb, kbp, lens, out_scores, out_attn);
    context_kernel<<<dim3(8, NBH), 256, 0, stream>>>(out_attn, v1b, ctx_ws);
    cat_kernel<<<(NB * NH * NS) / 64, 256, 0, stream>>>(ctx_ws, vtb, Wcat, bcat, out_ctx2);
    hipMemcpyAsync(out_ctx, ctx_ws, (size_t)QKV_ELEMS * sizeof(float),
                   hipMemcpyDeviceToDevice, stream);
}

// Round 4
// 512.517 us; speedup vs baseline: 2.0236x; 1.0658x over previous
//
#include <hip/hip_runtime.h>
#include <cstddef>

#define NB 8
#define NH 16
#define NS 512
#define NDH 64
#define NHID 1024
#define NBH (NB*NH)

#define QKV_ELEMS (NB*NH*NS*NDH)                 /* 4194304 */
#define ATTN_ELEMS ((size_t)NB*NH*(size_t)NS*NS) /* 33554432 */

typedef __bf16 bf16;
typedef __attribute__((ext_vector_type(8))) __bf16 bf16x8;
typedef __attribute__((ext_vector_type(4))) __bf16 bf16x4;
typedef __attribute__((ext_vector_type(4))) float f32x4;
typedef unsigned int u32;

// async global->LDS, 16B per lane. LDS dest must be WAVE-UNIFORM base; HW
// writes base + lane*16. Global src is per-lane. (m97 pattern, 874 TF.)
__device__ __forceinline__ void gload_lds16(const void* g, void* l) {
    __builtin_amdgcn_global_load_lds(
        (const __attribute__((address_space(1))) u32*)g,
        (__attribute__((address_space(3))) u32*)l, 16, 0, 0);
}

// XOR swizzle (short units) for reg-staged tiles (attn/context kernels)
__device__ __forceinline__ int swz(int idx, int row) { return idx ^ ((row & 7) << 3); }

// ---------------------------------------------------------------------------
// K0: per-sample valid lengths (first zero index, else S). lens[0..7]=q, [8..15]=k
__global__ void lens_kernel(const int* __restrict__ pq, const int* __restrict__ pk,
                            int* __restrict__ lens) {
    int bi = blockIdx.x;
    const int* v = (bi < NB) ? pq : pk;
    int b = bi & (NB - 1);
    int lane = threadIdx.x;
    int local = NS;
#pragma unroll
    for (int p = 0; p < NS / 64; ++p) {
        int idx = p * 64 + lane;
        if (v[b * NS + idx] == 0 && idx < local) local = idx;
    }
#pragma unroll
    for (int m = 32; m >= 1; m >>= 1) {
        int o = __shfl_xor(local, m, 64);
        local = min(local, o);
    }
    if (lane == 0) lens[bi] = local;
}

// ---------------------------------------------------------------------------
// K1: convert hidden states fp32 [B,H,S,DH] -> bf16 A-matrix [m=b*S+s][c=h*64+d]
__global__ __launch_bounds__(256) void cvtA_kernel(
    const float* __restrict__ hl, const float* __restrict__ hc,
    bf16* __restrict__ al, bf16* __restrict__ ac) {
    const float* src = blockIdx.z ? hc : hl;
    bf16* dst = blockIdx.z ? ac : al;
    int tid = blockIdx.x * 256 + threadIdx.x;      // 524288 threads
    int d8 = tid & 7, s = (tid >> 3) & 511, h = (tid >> 12) & 15, b = tid >> 16;
    const float* p = &src[(((size_t)b * NH + h) * NS + s) * NDH + d8 * 8];
    float4 v0 = *(const float4*)p;
    float4 v1 = *(const float4*)(p + 4);
    bf16x8 o;
    o[0] = (bf16)v0.x; o[1] = (bf16)v0.y; o[2] = (bf16)v0.z; o[3] = (bf16)v0.w;
    o[4] = (bf16)v1.x; o[5] = (bf16)v1.y; o[6] = (bf16)v1.z; o[7] = (bf16)v1.w;
    *(bf16x8*)&dst[((size_t)(b * NS + s)) * NHID + h * NDH + d8 * 8] = o;
}

// ---------------------------------------------------------------------------
// K2: transpose weights fp32 [k][n] -> bf16 Wt[z][n][k]
__global__ __launch_bounds__(256) void cvtW_kernel(
    const float* __restrict__ Wq, const float* __restrict__ Wk,
    const float* __restrict__ Wv1, const float* __restrict__ Wv,
    bf16* __restrict__ Wt) {
    const float* W;
    switch (blockIdx.z) {
        case 0: W = Wq; break;
        case 1: W = Wk; break;
        case 2: W = Wv1; break;
        default: W = Wv; break;
    }
    bf16* out = Wt + (size_t)blockIdx.z * NHID * NHID;
    __shared__ bf16 T[64][72];
    int t = threadIdx.x;
    int k0 = blockIdx.y * 64, n0 = blockIdx.x * 64;
#pragma unroll
    for (int p = 0; p < 4; ++p) {
        int kk = p * 16 + (t >> 4), c4 = (t & 15) * 4;
        float4 v = *(const float4*)&W[(size_t)(k0 + kk) * NHID + n0 + c4];
        T[c4 + 0][kk] = (bf16)v.x;
        T[c4 + 1][kk] = (bf16)v.y;
        T[c4 + 2][kk] = (bf16)v.z;
        T[c4 + 3][kk] = (bf16)v.w;
    }
    __syncthreads();
#pragma unroll
    for (int p = 0; p < 2; ++p) {
        int f = p * 256 + t;
        int nn = f >> 3, k8 = (f & 7) * 8;
        bf16x8 o;
#pragma unroll
        for (int e = 0; e < 8; ++e) o[e] = T[nn][k8 + e];
        *(bf16x8*)&out[(size_t)(n0 + nn) * NHID + k0 + k8] = o;
    }
}

// ---------------------------------------------------------------------------
// K3: 4 projection GEMMs, bf16 MFMA, global_load_lds staging (m97 structure).
// A [4096][1024] bf16, Wt [n][k] bf16. 128x128 tile, BK=64, 4 waves.
__global__ __launch_bounds__(256) void proj_kernel(
    const bf16* __restrict__ al, const bf16* __restrict__ ac,
    const bf16* __restrict__ Wt,
    const float* __restrict__ bq, const float* __restrict__ bk,
    const float* __restrict__ bv1, const float* __restrict__ bv,
    bf16* __restrict__ oq, bf16* __restrict__ ok,
    bf16* __restrict__ ov1, bf16* __restrict__ ovt) {
    __shared__ bf16 As[128 * 64];
    __shared__ bf16 Bs[128 * 64];
    const bf16* A; const bf16* W; const float* bias; bf16* dst;
    switch (blockIdx.z) {
        case 0: A = al; W = Wt;                 bias = bq;  dst = oq;  break;
        case 1: A = ac; W = Wt + 1048576;       bias = bk;  dst = ok;  break;
        case 2: A = al; W = Wt + 2097152;       bias = bv1; dst = ov1; break;
        default: A = ac; W = Wt + 3145728;      bias = bv;  dst = ovt; break;
    }
    int t = threadIdx.x, lane = t & 63, w = t >> 6;
    int wm = w & 1, wn = w >> 1;
    int m0 = blockIdx.y * 128, n0 = blockIdx.x * 128;
    int lrow = lane >> 3, lk8 = (lane & 7) * 8;
    f32x4 acc[4][4];
#pragma unroll
    for (int i = 0; i < 4; ++i)
#pragma unroll
        for (int j = 0; j < 4; ++j) acc[i][j] = (f32x4){0.f, 0.f, 0.f, 0.f};

    for (int kb = 0; kb < NHID; kb += 64) {
#pragma unroll
        for (int i = 0; i < 4; ++i) {
            int seg = w * 2048 + i * 512;              // elems; wave-uniform
            int row = (w * 32 + i * 8) + lrow;         // tile row this lane loads
            gload_lds16(&A[(size_t)(m0 + row) * NHID + kb + lk8], &As[seg]);
            gload_lds16(&W[(size_t)(n0 + row) * NHID + kb + lk8], &Bs[seg]);
        }
        __syncthreads();
#pragma unroll
        for (int ks = 0; ks < 2; ++ks) {
            int ko = ks * 32 + (lane >> 4) * 8;
            bf16x8 a[4], bb[4];
#pragma unroll
            for (int i = 0; i < 4; ++i)
                a[i] = *(const bf16x8*)&As[(wm * 64 + i * 16 + (lane & 15)) * 64 + ko];
#pragma unroll
            for (int j = 0; j < 4; ++j)
                bb[j] = *(const bf16x8*)&Bs[(wn * 64 + j * 16 + (lane & 15)) * 64 + ko];
#pragma unroll
            for (int i = 0; i < 4; ++i)
#pragma unroll
                for (int j = 0; j < 4; ++j)
                    acc[i][j] = __builtin_amdgcn_mfma_f32_16x16x32_bf16(a[i], bb[j], acc[i][j], 0, 0, 0);
        }
        __syncthreads();
    }
    float bsv[4];
#pragma unroll
    for (int j = 0; j < 4; ++j) bsv[j] = bias[n0 + wn * 64 + j * 16 + (lane & 15)];
#pragma unroll
    for (int i = 0; i < 4; ++i)
#pragma unroll
        for (int r = 0; r < 4; ++r) {
            int m = m0 + wm * 64 + i * 16 + (lane >> 4) * 4 + r;
            int b = m >> 9, s = m & (NS - 1);
#pragma unroll
            for (int j = 0; j < 4; ++j) {
                int n = n0 + wn * 64 + j * 16 + (lane & 15);
                dst[(((size_t)b * NH + (n >> 6)) * NS + s) * NDH + (n & 63)] =
                    (bf16)(acc[i][j][r] + bsv[j]);
            }
        }
}

// ---------------------------------------------------------------------------
// K4: fused scores + masked softmax. Per block: 64 ki x 512 qi for one bh.
__global__ __launch_bounds__(256) void attn_kernel(
    const bf16* __restrict__ qb, const bf16* __restrict__ kb,
    const int* __restrict__ lens,
    float* __restrict__ scores, float* __restrict__ attn) {
    __shared__ bf16 Ks[64 * 64];
    __shared__ float redm[4][64];
    __shared__ float reds[4][64];
    int bh = blockIdx.y, ki0 = blockIdx.x * 64;
    int b = bh >> 4;
    int t = threadIdx.x, lane = t & 63, w = t >> 6;
    int lq = lens[b], lk = lens[NB + b];
    const bf16* kbb = kb + ((size_t)bh * NS + ki0) * NDH;
    const bf16* qbb = qb + (size_t)bh * NS * NDH;
#pragma unroll
    for (int p = 0; p < 2; ++p) {
        int f = p * 256 + t;
        int row = f >> 3, d8 = (f & 7) * 8;
        bf16x8 v = *(const bf16x8*)&kbb[(size_t)row * NDH + d8];
        *(bf16x8*)&Ks[swz(row * 64 + d8, row)] = v;
    }
    __syncthreads();
    f32x4 acc[4][8];
#pragma unroll
    for (int i = 0; i < 4; ++i)
#pragma unroll
        for (int j = 0; j < 8; ++j) acc[i][j] = (f32x4){0.f, 0.f, 0.f, 0.f};
#pragma unroll
    for (int ds = 0; ds < 2; ++ds) {
        int kofs = ds * 32 + (lane >> 4) * 8;
        bf16x8 a[4];
#pragma unroll
        for (int i = 0; i < 4; ++i) {
            int row = i * 16 + (lane & 15);
            a[i] = *(const bf16x8*)&Ks[swz(row * 64 + kofs, row)];
        }
#pragma unroll
        for (int j = 0; j < 8; ++j) {
            int qi = w * 128 + j * 16 + (lane & 15);
            bf16x8 bq8 = *(const bf16x8*)&qbb[(size_t)qi * NDH + kofs];
#pragma unroll
            for (int i = 0; i < 4; ++i)
                acc[i][j] = __builtin_amdgcn_mfma_f32_16x16x32_bf16(a[i], bq8, acc[i][j], 0, 0, 0);
        }
    }
    int g = lane >> 4, c = lane & 15;
    float pmax[4][4];
#pragma unroll
    for (int i = 0; i < 4; ++i)
#pragma unroll
        for (int r = 0; r < 4; ++r) pmax[i][r] = -3.0e38f;
#pragma unroll
    for (int i = 0; i < 4; ++i)
#pragma unroll
        for (int j = 0; j < 8; ++j) {
            int qi = w * 128 + j * 16 + c;
            bool colv = qi < lk;
#pragma unroll
            for (int r = 0; r < 4; ++r) {
                float s = acc[i][j][r] * 0.125f;
                acc[i][j][r] = s;
                scores[((size_t)bh * NS + ki0 + i * 16 + g * 4 + r) * NS + qi] = s;
                if (colv) pmax[i][r] = fmaxf(pmax[i][r], s);
            }
        }
#pragma unroll
    for (int msk = 8; msk >= 1; msk >>= 1)
#pragma unroll
        for (int i = 0; i < 4; ++i)
#pragma unroll
            for (int r = 0; r < 4; ++r)
                pmax[i][r] = fmaxf(pmax[i][r], __shfl_xor(pmax[i][r], msk, 64));
    if (c == 0)
#pragma unroll
        for (int i = 0; i < 4; ++i)
#pragma unroll
            for (int r = 0; r < 4; ++r) redm[w][i * 16 + g * 4 + r] = pmax[i][r];
    __syncthreads();
    float rmax[4][4];
#pragma unroll
    for (int i = 0; i < 4; ++i)
#pragma unroll
        for (int r = 0; r < 4; ++r) {
            int row = i * 16 + g * 4 + r;
            rmax[i][r] = fmaxf(fmaxf(redm[0][row], redm[1][row]),
                               fmaxf(redm[2][row], redm[3][row]));
        }
    float psum[4][4];
#pragma unroll
    for (int i = 0; i < 4; ++i)
#pragma unroll
        for (int r = 0; r < 4; ++r) psum[i][r] = 0.f;
#pragma unroll
    for (int i = 0; i < 4; ++i)
#pragma unroll
        for (int j = 0; j < 8; ++j) {
            int qi = w * 128 + j * 16 + c;
            bool colv = qi < lk;
#pragma unroll
            for (int r = 0; r < 4; ++r) {
                float e = colv ? __expf(acc[i][j][r] - rmax[i][r]) : 0.f;
                acc[i][j][r] = e;
                psum[i][r] += e;
            }
        }
#pragma unroll
    for (int msk = 8; msk >= 1; msk >>= 1)
#pragma unroll
        for (int i = 0; i < 4; ++i)
#pragma unroll
            for (int r = 0; r < 4; ++r)
                psum[i][r] += __shfl_xor(psum[i][r], msk, 64);
    if (c == 0)
#pragma unroll
        for (int i = 0; i < 4; ++i)
#pragma unroll
            for (int r = 0; r < 4; ++r) reds[w][i * 16 + g * 4 + r] = psum[i][r];
    __syncthreads();
#pragma unroll
    for (int i = 0; i < 4; ++i)
#pragma unroll
        for (int r = 0; r < 4; ++r) {
            int row = i * 16 + g * 4 + r;
            float rs = reds[0][row] + reds[1][row] + reds[2][row] + reds[3][row];
            float inv = (rs > 0.f) ? 1.f / rs : 0.f;
            bool rowv = (ki0 + row) < lq;
#pragma unroll
            for (int j = 0; j < 8; ++j) {
                int qi = w * 128 + j * 16 + c;
                float v = rowv ? acc[i][j][r] * inv : 0.f;
                attn[((size_t)bh * NS + ki0 + row) * NS + qi] = v;
            }
        }
}

// ---------------------------------------------------------------------------
// K5: context = attn @ v1 (bf16 MFMA)
__global__ __launch_bounds__(256) void context_kernel(
    const float* __restrict__ attn, const bf16* __restrict__ v1,
    float* __restrict__ ctx) {
    __shared__ bf16 Ash[64 * 64];
    __shared__ bf16 Vs[64 * 64];
    int bh = blockIdx.y, ki0 = blockIdx.x * 64;
    int t = threadIdx.x, lane = t & 63, w = t >> 6;
    const float* ab = attn + ((size_t)bh * NS + ki0) * NS;
    const bf16* vb = v1 + (size_t)bh * NS * NDH;
    f32x4 acc[4];
#pragma unroll
    for (int j = 0; j < 4; ++j) acc[j] = (f32x4){0.f, 0.f, 0.f, 0.f};

    for (int q0 = 0; q0 < NS; q0 += 64) {
#pragma unroll
        for (int p = 0; p < 4; ++p) {
            int f = p * 256 + t;
            int row = f >> 4, c4 = (f & 15) * 4;
            float4 v = *(const float4*)&ab[(size_t)row * NS + q0 + c4];
            bf16x4 h;
            h[0] = (bf16)v.x; h[1] = (bf16)v.y; h[2] = (bf16)v.z; h[3] = (bf16)v.w;
            *(bf16x4*)&Ash[swz(row * 64 + c4, row)] = h;
        }
#pragma unroll
        for (int p = 0; p < 2; ++p) {
            int f = p * 256 + t;
            int qr = f >> 3, d8 = (f & 7) * 8;
            bf16x8 v = *(const bf16x8*)&vb[(size_t)(q0 + qr) * NDH + d8];
#pragma unroll
            for (int e = 0; e < 8; ++e) {
                int d = d8 + e;
                Vs[swz(d * 64 + qr, d)] = v[e];
            }
        }
        __syncthreads();
#pragma unroll
        for (int kk = 0; kk < 2; ++kk) {
            int kofs = kk * 32 + (lane >> 4) * 8;
            int arow = w * 16 + (lane & 15);
            bf16x8 a = *(const bf16x8*)&Ash[swz(arow * 64 + kofs, arow)];
#pragma unroll
            for (int j = 0; j < 4; ++j) {
                int d = j * 16 + (lane & 15);
                bf16x8 bv8 = *(const bf16x8*)&Vs[swz(d * 64 + kofs, d)];
                acc[j] = __builtin_amdgcn_mfma_f32_16x16x32_bf16(a, bv8, acc[j], 0, 0, 0);
            }
        }
        __syncthreads();
    }
    int g = lane >> 4, c = lane & 15;
#pragma unroll
    for (int j = 0; j < 4; ++j)
#pragma unroll
        for (int r = 0; r < 4; ++r) {
            int ki = ki0 + w * 16 + g * 4 + r;
            ctx[((size_t)bh * NS + ki) * NDH + j * 16 + c] = acc[j][r];
        }
}

// ---------------------------------------------------------------------------
// K6: context2 = concat([ctx, vt], -1) @ W_cat + b_cat  (fp32, small)
__global__ __launch_bounds__(256) void cat_kernel(
    const float* __restrict__ ctx, const bf16* __restrict__ vt,
    const float* __restrict__ Wcat, const float* __restrict__ bcat,
    float* __restrict__ out) {
    __shared__ float As[16][68];
    __shared__ float Bs[16][68];
    int t = threadIdx.x;
    int tx = t & 15, ty = t >> 4;
    int row0 = blockIdx.x * 64;
    float acc[4][4];
#pragma unroll
    for (int i = 0; i < 4; ++i)
#pragma unroll
        for (int j = 0; j < 4; ++j) acc[i][j] = 0.f;

    for (int k0 = 0; k0 < 2 * NDH; k0 += 16) {
#pragma unroll
        for (int p = 0; p < 4; ++p) {
            int e = p * 256 + t;
            int kk = e & 15, mm = e >> 4;
            int cidx = k0 + kk;
            float val = (cidx < NDH) ? ctx[(size_t)(row0 + mm) * NDH + cidx]
                                     : (float)vt[(size_t)(row0 + mm) * NDH + (cidx - NDH)];
            As[kk][mm] = val;
        }
#pragma unroll
        for (int p = 0; p < 4; ++p) {
            int e = p * 256 + t;
            int nn = e & 63, kk = e >> 6;
            Bs[kk][nn] = Wcat[(size_t)(k0 + kk) * NDH + nn];
        }
        __syncthreads();
#pragma unroll
        for (int kk = 0; kk < 16; ++kk) {
            float a[4], bb[4];
            *(float4*)&a[0]  = *(const float4*)&As[kk][ty * 4];
            *(float4*)&bb[0] = *(const float4*)&Bs[kk][tx * 4];
#pragma unroll
            for (int i = 0; i < 4; ++i)
#pragma unroll
                for (int j = 0; j < 4; ++j) acc[i][j] += a[i] * bb[j];
        }
        __syncthreads();
    }
#pragma unroll
    for (int i = 0; i < 4; ++i) {
        int n = tx * 4;
        float4 o;
        o.x = acc[i][0] + bcat[n + 0];
        o.y = acc[i][1] + bcat[n + 1];
        o.z = acc[i][2] + bcat[n + 2];
        o.w = acc[i][3] + bcat[n + 3];
        *(float4*)&out[(size_t)(row0 + ty * 4 + i) * NDH + n] = o;
    }
}

// ---------------------------------------------------------------------------
extern "C" void kernel_launch(void* const* d_in, const int* in_sizes, int n_in,
                              void* d_out, int out_size, void* d_ws, size_t ws_size,
                              hipStream_t stream) {
    (void)in_sizes; (void)n_in; (void)out_size; (void)ws_size;
    const int*   pq   = (const int*)d_in[0];
    const int*   pk   = (const int*)d_in[1];
    const float* hl   = (const float*)d_in[6];
    const float* hc   = (const float*)d_in[7];
    const float* Wv1  = (const float*)d_in[11];
    const float* bv1  = (const float*)d_in[12];
    const float* Wv   = (const float*)d_in[13];
    const float* bv   = (const float*)d_in[14];
    const float* Wq   = (const float*)d_in[15];
    const float* bq   = (const float*)d_in[16];
    const float* Wk   = (const float*)d_in[17];
    const float* bk   = (const float*)d_in[18];
    const float* Wcat = (const float*)d_in[19];
    const float* bcat = (const float*)d_in[20];

    float* out_attn   = (float*)d_out;             // [B,H,S,S]
    float* out_scores = out_attn + ATTN_ELEMS;     // [B,H,S,S]
    float* out_ctx2   = out_attn + 2 * ATTN_ELEMS; // [B,H,S,DH]
    float* out_ctx    = out_ctx2 + QKV_ELEMS;      // [B,H,S,DH]

    // ws layout (bytes): all bf16 intermediates live in workspace (~58.7 MB).
    char* ws = (char*)d_ws;
    bf16* al   = (bf16*)(ws);                        // A_last  [4096][1024]
    bf16* acb  = (bf16*)(ws + 8388608);              // A_cur
    bf16* WtB  = (bf16*)(ws + 16777216);             // Wt [4][1024][1024]
    bf16* qb   = (bf16*)(ws + 25165824);
    bf16* kbp  = (bf16*)(ws + 33554432);
    bf16* v1b  = (bf16*)(ws + 41943040);
    bf16* vtb  = (bf16*)(ws + 50331648);
    int*  lens = (int*)(ws + 58720256);

    lens_kernel<<<16, 64, 0, stream>>>(pq, pk, lens);
    cvtA_kernel<<<dim3(2048, 1, 2), 256, 0, stream>>>(hl, hc, al, acb);
    cvtW_kernel<<<dim3(16, 16, 4), 256, 0, stream>>>(Wq, Wk, Wv1, Wv, WtB);
    proj_kernel<<<dim3(8, 32, 4), 256, 0, stream>>>(
        al, acb, WtB, bq, bk, bv1, bv, qb, kbp, v1b, vtb);
    attn_kernel<<<dim3(8, NBH), 256, 0, stream>>>(qb, kbp, lens, out_scores, out_attn);
    context_kernel<<<dim3(8, NBH), 256, 0, stream>>>(out_attn, v1b, out_ctx);
    cat_kernel<<<(NB * NH * NS) / 64, 256, 0, stream>>>(out_ctx, vtb, Wcat, bcat, out_ctx2);
}

// Round 7
// 495.865 us; speedup vs baseline: 2.0916x; 1.0336x over previous
//
#include <hip/hip_runtime.h>
#include <cstddef>

#define NB 8
#define NH 16
#define NS 512
#define NDH 64
#define NHID 1024
#define NBH (NB*NH)

#define QKV_ELEMS (NB*NH*NS*NDH)                 /* 4194304 */
#define ATTN_ELEMS ((size_t)NB*NH*(size_t)NS*NS) /* 33554432 */

typedef __bf16 bf16;
typedef __attribute__((ext_vector_type(8))) __bf16 bf16x8;
typedef __attribute__((ext_vector_type(4))) __bf16 bf16x4;
typedef __attribute__((ext_vector_type(4))) float f32x4;
typedef unsigned int u32;

// async global->LDS, 16B per lane. LDS dest must be WAVE-UNIFORM base; HW
// writes base + lane*16. Global src is per-lane. (m97 pattern, 874 TF.)
__device__ __forceinline__ void gload_lds16(const void* g, void* l) {
    __builtin_amdgcn_global_load_lds(
        (const __attribute__((address_space(1))) u32*)g,
        (__attribute__((address_space(3))) u32*)l, 16, 0, 0);
}

// XOR swizzle (short units): spreads 8 rows of a 128B/256B-stride tile across
// banks while keeping 8-short contiguity (G4 recipe).
__device__ __forceinline__ int swz(int idx, int row) { return idx ^ ((row & 7) << 3); }

// ---------------------------------------------------------------------------
// K0: per-sample valid lengths (first zero index, else S). lens[0..7]=q, [8..15]=k
__global__ void lens_kernel(const int* __restrict__ pq, const int* __restrict__ pk,
                            int* __restrict__ lens) {
    int bi = blockIdx.x;
    const int* v = (bi < NB) ? pq : pk;
    int b = bi & (NB - 1);
    int lane = threadIdx.x;
    int local = NS;
#pragma unroll
    for (int p = 0; p < NS / 64; ++p) {
        int idx = p * 64 + lane;
        if (v[b * NS + idx] == 0 && idx < local) local = idx;
    }
#pragma unroll
    for (int m = 32; m >= 1; m >>= 1) {
        int o = __shfl_xor(local, m, 64);
        local = min(local, o);
    }
    if (lane == 0) lens[bi] = local;
}

// ---------------------------------------------------------------------------
// K1: convert hidden states fp32 [B,H,S,DH] -> bf16 A-matrix [m=b*S+s][c=h*64+d]
__global__ __launch_bounds__(256) void cvtA_kernel(
    const float* __restrict__ hl, const float* __restrict__ hc,
    bf16* __restrict__ al, bf16* __restrict__ ac) {
    const float* src = blockIdx.z ? hc : hl;
    bf16* dst = blockIdx.z ? ac : al;
    int tid = blockIdx.x * 256 + threadIdx.x;      // 524288 threads
    int d8 = tid & 7, s = (tid >> 3) & 511, h = (tid >> 12) & 15, b = tid >> 16;
    const float* p = &src[(((size_t)b * NH + h) * NS + s) * NDH + d8 * 8];
    float4 v0 = *(const float4*)p;
    float4 v1 = *(const float4*)(p + 4);
    bf16x8 o;
    o[0] = (bf16)v0.x; o[1] = (bf16)v0.y; o[2] = (bf16)v0.z; o[3] = (bf16)v0.w;
    o[4] = (bf16)v1.x; o[5] = (bf16)v1.y; o[6] = (bf16)v1.z; o[7] = (bf16)v1.w;
    *(bf16x8*)&dst[((size_t)(b * NS + s)) * NHID + h * NDH + d8 * 8] = o;
}

// ---------------------------------------------------------------------------
// K2: transpose weights fp32 [k][n] -> bf16 Wt[z][n][k]
__global__ __launch_bounds__(256) void cvtW_kernel(
    const float* __restrict__ Wq, const float* __restrict__ Wk,
    const float* __restrict__ Wv1, const float* __restrict__ Wv,
    bf16* __restrict__ Wt) {
    const float* W;
    switch (blockIdx.z) {
        case 0: W = Wq; break;
        case 1: W = Wk; break;
        case 2: W = Wv1; break;
        default: W = Wv; break;
    }
    bf16* out = Wt + (size_t)blockIdx.z * NHID * NHID;
    __shared__ bf16 T[64][72];
    int t = threadIdx.x;
    int k0 = blockIdx.y * 64, n0 = blockIdx.x * 64;
#pragma unroll
    for (int p = 0; p < 4; ++p) {
        int kk = p * 16 + (t >> 4), c4 = (t & 15) * 4;
        float4 v = *(const float4*)&W[(size_t)(k0 + kk) * NHID + n0 + c4];
        T[c4 + 0][kk] = (bf16)v.x;
        T[c4 + 1][kk] = (bf16)v.y;
        T[c4 + 2][kk] = (bf16)v.z;
        T[c4 + 3][kk] = (bf16)v.w;
    }
    __syncthreads();
#pragma unroll
    for (int p = 0; p < 2; ++p) {
        int f = p * 256 + t;
        int nn = f >> 3, k8 = (f & 7) * 8;
        bf16x8 o;
#pragma unroll
        for (int e = 0; e < 8; ++e) o[e] = T[nn][k8 + e];
        *(bf16x8*)&out[(size_t)(n0 + nn) * NHID + k0 + k8] = o;
    }
}

// ---------------------------------------------------------------------------
// K3: 4 projection GEMMs, bf16 MFMA, global_load_lds staging (m97 structure).
__global__ __launch_bounds__(256) void proj_kernel(
    const bf16* __restrict__ al, const bf16* __restrict__ ac,
    const bf16* __restrict__ Wt,
    const float* __restrict__ bq, const float* __restrict__ bk,
    const float* __restrict__ bv1, const float* __restrict__ bv,
    bf16* __restrict__ oq, bf16* __restrict__ ok,
    bf16* __restrict__ ov1, bf16* __restrict__ ovt) {
    __shared__ bf16 As[128 * 64];
    __shared__ bf16 Bs[128 * 64];
    const bf16* A; const bf16* W; const float* bias; bf16* dst;
    switch (blockIdx.z) {
        case 0: A = al; W = Wt;                 bias = bq;  dst = oq;  break;
        case 1: A = ac; W = Wt + 1048576;       bias = bk;  dst = ok;  break;
        case 2: A = al; W = Wt + 2097152;       bias = bv1; dst = ov1; break;
        default: A = ac; W = Wt + 3145728;      bias = bv;  dst = ovt; break;
    }
    int t = threadIdx.x, lane = t & 63, w = t >> 6;
    int wm = w & 1, wn = w >> 1;
    int m0 = blockIdx.y * 128, n0 = blockIdx.x * 128;
    int lrow = lane >> 3, lk8 = (lane & 7) * 8;
    f32x4 acc[4][4];
#pragma unroll
    for (int i = 0; i < 4; ++i)
#pragma unroll
        for (int j = 0; j < 4; ++j) acc[i][j] = (f32x4){0.f, 0.f, 0.f, 0.f};

    for (int kb = 0; kb < NHID; kb += 64) {
#pragma unroll
        for (int i = 0; i < 4; ++i) {
            int seg = w * 2048 + i * 512;              // elems; wave-uniform
            int row = (w * 32 + i * 8) + lrow;         // tile row this lane loads
            gload_lds16(&A[(size_t)(m0 + row) * NHID + kb + lk8], &As[seg]);
            gload_lds16(&W[(size_t)(n0 + row) * NHID + kb + lk8], &Bs[seg]);
        }
        __syncthreads();
#pragma unroll
        for (int ks = 0; ks < 2; ++ks) {
            int ko = ks * 32 + (lane >> 4) * 8;
            bf16x8 a[4], bb[4];
#pragma unroll
            for (int i = 0; i < 4; ++i)
                a[i] = *(const bf16x8*)&As[(wm * 64 + i * 16 + (lane & 15)) * 64 + ko];
#pragma unroll
            for (int j = 0; j < 4; ++j)
                bb[j] = *(const bf16x8*)&Bs[(wn * 64 + j * 16 + (lane & 15)) * 64 + ko];
#pragma unroll
            for (int i = 0; i < 4; ++i)
#pragma unroll
                for (int j = 0; j < 4; ++j)
                    acc[i][j] = __builtin_amdgcn_mfma_f32_16x16x32_bf16(a[i], bb[j], acc[i][j], 0, 0, 0);
        }
        __syncthreads();
    }
    float bsv[4];
#pragma unroll
    for (int j = 0; j < 4; ++j) bsv[j] = bias[n0 + wn * 64 + j * 16 + (lane & 15)];
#pragma unroll
    for (int i = 0; i < 4; ++i)
#pragma unroll
        for (int r = 0; r < 4; ++r) {
            int m = m0 + wm * 64 + i * 16 + (lane >> 4) * 4 + r;
            int b = m >> 9, s = m & (NS - 1);
#pragma unroll
            for (int j = 0; j < 4; ++j) {
                int n = n0 + wn * 64 + j * 16 + (lane & 15);
                dst[(((size_t)b * NH + (n >> 6)) * NS + s) * NDH + (n & 63)] =
                    (bf16)(acc[i][j][r] + bsv[j]);
            }
        }
}

// ---------------------------------------------------------------------------
// K4: fused scores + masked softmax + PV context. Per block: 64 ki x 512 qi.
// Writes scores_t (raw/8), attn (masked softmax), ctx (= attn @ v1).
__global__ __launch_bounds__(256) void attn_fused_kernel(
    const bf16* __restrict__ qb, const bf16* __restrict__ kb,
    const bf16* __restrict__ v1, const int* __restrict__ lens,
    float* __restrict__ scores, float* __restrict__ attn,
    float* __restrict__ ctx) {
    __shared__ bf16 Ks[64 * 64];        // 8 KB   [ki][d]
    __shared__ bf16 Ps[64 * 128];       // 16 KB  [ki][qc]   (one 128-qi chunk)
    __shared__ bf16 Vs[64 * 128];       // 16 KB  [d][qc]
    __shared__ float redm[4][64];
    __shared__ float reds[4][64];
    int bh = blockIdx.y, ki0 = blockIdx.x * 64;
    int b = bh >> 4;
    int t = threadIdx.x, lane = t & 63, w = t >> 6;
    int lq = lens[b], lk = lens[NB + b];
    const bf16* kbb = kb + ((size_t)bh * NS + ki0) * NDH;
    const bf16* qbb = qb + (size_t)bh * NS * NDH;
    const bf16* vb  = v1 + (size_t)bh * NS * NDH;
#pragma unroll
    for (int p = 0; p < 2; ++p) {              // K tile 64x64
        int f = p * 256 + t;
        int row = f >> 3, d8 = (f & 7) * 8;
        bf16x8 v = *(const bf16x8*)&kbb[(size_t)row * NDH + d8];
        *(bf16x8*)&Ks[swz(row * 64 + d8, row)] = v;
    }
    __syncthreads();
    f32x4 acc[4][8];
#pragma unroll
    for (int i = 0; i < 4; ++i)
#pragma unroll
        for (int j = 0; j < 8; ++j) acc[i][j] = (f32x4){0.f, 0.f, 0.f, 0.f};
#pragma unroll
    for (int ds = 0; ds < 2; ++ds) {
        int kofs = ds * 32 + (lane >> 4) * 8;
        bf16x8 a[4];
#pragma unroll
        for (int i = 0; i < 4; ++i) {
            int row = i * 16 + (lane & 15);
            a[i] = *(const bf16x8*)&Ks[swz(row * 64 + kofs, row)];
        }
#pragma unroll
        for (int j = 0; j < 8; ++j) {
            int qi = w * 128 + j * 16 + (lane & 15);
            bf16x8 bq8 = *(const bf16x8*)&qbb[(size_t)qi * NDH + kofs];
#pragma unroll
            for (int i = 0; i < 4; ++i)
                acc[i][j] = __builtin_amdgcn_mfma_f32_16x16x32_bf16(a[i], bq8, acc[i][j], 0, 0, 0);
        }
    }
    int g = lane >> 4, c = lane & 15;
    // scale + raw scores write + masked row-max
    float pmax[4][4];
#pragma unroll
    for (int i = 0; i < 4; ++i)
#pragma unroll
        for (int r = 0; r < 4; ++r) pmax[i][r] = -3.0e38f;
#pragma unroll
    for (int i = 0; i < 4; ++i)
#pragma unroll
        for (int j = 0; j < 8; ++j) {
            int qi = w * 128 + j * 16 + c;
            bool colv = qi < lk;
#pragma unroll
            for (int r = 0; r < 4; ++r) {
                float s = acc[i][j][r] * 0.125f;
                acc[i][j][r] = s;
                scores[((size_t)bh * NS + ki0 + i * 16 + g * 4 + r) * NS + qi] = s;
                if (colv) pmax[i][r] = fmaxf(pmax[i][r], s);
            }
        }
#pragma unroll
    for (int msk = 8; msk >= 1; msk >>= 1)
#pragma unroll
        for (int i = 0; i < 4; ++i)
#pragma unroll
            for (int r = 0; r < 4; ++r)
                pmax[i][r] = fmaxf(pmax[i][r], __shfl_xor(pmax[i][r], msk, 64));
    if (c == 0)
#pragma unroll
        for (int i = 0; i < 4; ++i)
#pragma unroll
            for (int r = 0; r < 4; ++r) redm[w][i * 16 + g * 4 + r] = pmax[i][r];
    __syncthreads();
    float rmax[4][4];
#pragma unroll
    for (int i = 0; i < 4; ++i)
#pragma unroll
        for (int r = 0; r < 4; ++r) {
            int row = i * 16 + g * 4 + r;
            rmax[i][r] = fmaxf(fmaxf(redm[0][row], redm[1][row]),
                               fmaxf(redm[2][row], redm[3][row]));
        }
    float psum[4][4];
#pragma unroll
    for (int i = 0; i < 4; ++i)
#pragma unroll
        for (int r = 0; r < 4; ++r) psum[i][r] = 0.f;
#pragma unroll
    for (int i = 0; i < 4; ++i)
#pragma unroll
        for (int j = 0; j < 8; ++j) {
            int qi = w * 128 + j * 16 + c;
            bool colv = qi < lk;
#pragma unroll
            for (int r = 0; r < 4; ++r) {
                float e = colv ? __expf(acc[i][j][r] - rmax[i][r]) : 0.f;
                acc[i][j][r] = e;
                psum[i][r] += e;
            }
        }
#pragma unroll
    for (int msk = 8; msk >= 1; msk >>= 1)
#pragma unroll
        for (int i = 0; i < 4; ++i)
#pragma unroll
            for (int r = 0; r < 4; ++r)
                psum[i][r] += __shfl_xor(psum[i][r], msk, 64);
    if (c == 0)
#pragma unroll
        for (int i = 0; i < 4; ++i)
#pragma unroll
            for (int r = 0; r < 4; ++r) reds[w][i * 16 + g * 4 + r] = psum[i][r];
    __syncthreads();
    // finalize p in-register, write attn
#pragma unroll
    for (int i = 0; i < 4; ++i)
#pragma unroll
        for (int r = 0; r < 4; ++r) {
            int row = i * 16 + g * 4 + r;
            float rs = reds[0][row] + reds[1][row] + reds[2][row] + reds[3][row];
            float inv = (rs > 0.f) ? 1.f / rs : 0.f;
            bool rowv = (ki0 + row) < lq;
            float fin = rowv ? inv : 0.f;
#pragma unroll
            for (int j = 0; j < 8; ++j) {
                int qi = w * 128 + j * 16 + c;
                float v = acc[i][j][r] * fin;
                acc[i][j][r] = v;
                attn[((size_t)bh * NS + ki0 + row) * NS + qi] = v;
            }
        }
    // --- PV: ctx[64 ki][64 d] = P @ v1, chunked over qi (128 per chunk) ---
    if (ki0 >= lq) {                           // whole block masked -> ctx = 0
#pragma unroll
        for (int p = 0; p < 4; ++p) {
            int f = p * 256 + t;
            int row = f >> 4, c4 = (f & 15) * 4;
            *(float4*)&ctx[((size_t)bh * NS + ki0 + row) * NDH + c4] =
                make_float4(0.f, 0.f, 0.f, 0.f);
        }
        return;
    }
    f32x4 cacc[4];
#pragma unroll
    for (int j = 0; j < 4; ++j) cacc[j] = (f32x4){0.f, 0.f, 0.f, 0.f};
    for (int cq = 0; cq < 4; ++cq) {
        if (cq * 128 >= lk) break;             // tail chunks are all-zero P
        __syncthreads();                       // Ps/Vs free from previous chunk
#pragma unroll
        for (int p = 0; p < 4; ++p) {          // V chunk 128 qi x 64 d -> [d][qc]
            int f = p * 256 + t;
            int qr = f >> 3, d8 = (f & 7) * 8;
            bf16x8 v = *(const bf16x8*)&vb[(size_t)(cq * 128 + qr) * NDH + d8];
#pragma unroll
            for (int e = 0; e < 8; ++e)
                Vs[swz((d8 + e) * 128 + qr, d8 + e)] = v[e];
        }
        if (w == cq) {                         // publisher wave writes its P chunk
#pragma unroll
            for (int i = 0; i < 4; ++i)
#pragma unroll
                for (int j = 0; j < 8; ++j) {
                    int qc = j * 16 + c;
#pragma unroll
                    for (int r = 0; r < 4; ++r) {
                        int row = i * 16 + g * 4 + r;
                        Ps[swz(row * 128 + qc, row)] = (bf16)acc[i][j][r];
                    }
                }
        }
        __syncthreads();
#pragma unroll
        for (int ks = 0; ks < 4; ++ks) {       // K=128 per chunk
            int kofs = ks * 32 + (lane >> 4) * 8;
            int arow = w * 16 + (lane & 15);
            bf16x8 a = *(const bf16x8*)&Ps[swz(arow * 128 + kofs, arow)];
#pragma unroll
            for (int j = 0; j < 4; ++j) {
                int d = j * 16 + (lane & 15);
                bf16x8 bv8 = *(const bf16x8*)&Vs[swz(d * 128 + kofs, d)];
                cacc[j] = __builtin_amdgcn_mfma_f32_16x16x32_bf16(a, bv8, cacc[j], 0, 0, 0);
            }
        }
    }
#pragma unroll
    for (int j = 0; j < 4; ++j)
#pragma unroll
        for (int r = 0; r < 4; ++r) {
            int ki = ki0 + w * 16 + g * 4 + r;
            ctx[((size_t)bh * NS + ki) * NDH + j * 16 + c] = cacc[j][r];
        }
}

// ---------------------------------------------------------------------------
// K5: context2 = concat([ctx, vt], -1) @ W_cat + b_cat  (fp32, small)
__global__ __launch_bounds__(256) void cat_kernel(
    const float* __restrict__ ctx, const bf16* __restrict__ vt,
    const float* __restrict__ Wcat, const float* __restrict__ bcat,
    float* __restrict__ out) {
    __shared__ float As[16][68];
    __shared__ float Bs[16][68];
    int t = threadIdx.x;
    int tx = t & 15, ty = t >> 4;
    int row0 = blockIdx.x * 64;
    float acc[4][4];
#pragma unroll
    for (int i = 0; i < 4; ++i)
#pragma unroll
        for (int j = 0; j < 4; ++j) acc[i][j] = 0.f;

    for (int k0 = 0; k0 < 2 * NDH; k0 += 16) {
#pragma unroll
        for (int p = 0; p < 4; ++p) {
            int e = p * 256 + t;
            int kk = e & 15, mm = e >> 4;
            int cidx = k0 + kk;
            float val = (cidx < NDH) ? ctx[(size_t)(row0 + mm) * NDH + cidx]
                                     : (float)vt[(size_t)(row0 + mm) * NDH + (cidx - NDH)];
            As[kk][mm] = val;
        }
#pragma unroll
        for (int p = 0; p < 4; ++p) {
            int e = p * 256 + t;
            int nn = e & 63, kk = e >> 6;
            Bs[kk][nn] = Wcat[(size_t)(k0 + kk) * NDH + nn];
        }
        __syncthreads();
#pragma unroll
        for (int kk = 0; kk < 16; ++kk) {
            float a[4], bb[4];
            *(float4*)&a[0]  = *(const float4*)&As[kk][ty * 4];
            *(float4*)&bb[0] = *(const float4*)&Bs[kk][tx * 4];
#pragma unroll
            for (int i = 0; i < 4; ++i)
#pragma unroll
                for (int j = 0; j < 4; ++j) acc[i][j] += a[i] * bb[j];
        }
        __syncthreads();
    }
#pragma unroll
    for (int i = 0; i < 4; ++i) {
        int n = tx * 4;
        float4 o;
        o.x = acc[i][0] + bcat[n + 0];
        o.y = acc[i][1] + bcat[n + 1];
        o.z = acc[i][2] + bcat[n + 2];
        o.w = acc[i][3] + bcat[n + 3];
        *(float4*)&out[(size_t)(row0 + ty * 4 + i) * NDH + n] = o;
    }
}

// ---------------------------------------------------------------------------
extern "C" void kernel_launch(void* const* d_in, const int* in_sizes, int n_in,
                              void* d_out, int out_size, void* d_ws, size_t ws_size,
                              hipStream_t stream) {
    (void)in_sizes; (void)n_in; (void)out_size; (void)ws_size;
    const int*   pq   = (const int*)d_in[0];
    const int*   pk   = (const int*)d_in[1];
    const float* hl   = (const float*)d_in[6];
    const float* hc   = (const float*)d_in[7];
    const float* Wv1  = (const float*)d_in[11];
    const float* bv1  = (const float*)d_in[12];
    const float* Wv   = (const float*)d_in[13];
    const float* bv   = (const float*)d_in[14];
    const float* Wq   = (const float*)d_in[15];
    const float* bq   = (const float*)d_in[16];
    const float* Wk   = (const float*)d_in[17];
    const float* bk   = (const float*)d_in[18];
    const float* Wcat = (const float*)d_in[19];
    const float* bcat = (const float*)d_in[20];

    float* out_attn   = (float*)d_out;             // [B,H,S,S]
    float* out_scores = out_attn + ATTN_ELEMS;     // [B,H,S,S]
    float* out_ctx2   = out_attn + 2 * ATTN_ELEMS; // [B,H,S,DH]
    float* out_ctx    = out_ctx2 + QKV_ELEMS;      // [B,H,S,DH]

    // ws layout (bytes): all bf16 intermediates live in workspace (~58.7 MB).
    char* ws = (char*)d_ws;
    bf16* al   = (bf16*)(ws);                        // A_last  [4096][1024]
    bf16* acb  = (bf16*)(ws + 8388608);              // A_cur
    bf16* WtB  = (bf16*)(ws + 16777216);             // Wt [4][1024][1024]
    bf16* qb   = (bf16*)(ws + 25165824);
    bf16* kbp  = (bf16*)(ws + 33554432);
    bf16* v1b  = (bf16*)(ws + 41943040);
    bf16* vtb  = (bf16*)(ws + 50331648);
    int*  lens = (int*)(ws + 58720256);

    lens_kernel<<<16, 64, 0, stream>>>(pq, pk, lens);
    cvtA_kernel<<<dim3(2048, 1, 2), 256, 0, stream>>>(hl, hc, al, acb);
    cvtW_kernel<<<dim3(16, 16, 4), 256, 0, stream>>>(Wq, Wk, Wv1, Wv, WtB);
    proj_kernel<<<dim3(8, 32, 4), 256, 0, stream>>>(
        al, acb, WtB, bq, bk, bv1, bv, qb, kbp, v1b, vtb);
    attn_fused_kernel<<<dim3(8, NBH), 256, 0, stream>>>(
        qb, kbp, v1b, lens, out_scores, out_attn, out_ctx);
    cat_kernel<<<(NB * NH * NS) / 64, 256, 0, stream>>>(out_ctx, vtb, Wcat, bcat, out_ctx2);
}

// Round 10
// 484.030 us; speedup vs baseline: 2.1427x; 1.0245x over previous
//
#include <hip/hip_runtime.h>
#include <cstddef>

#define NB 8
#define NH 16
#define NS 512
#define NDH 64
#define NHID 1024
#define NBH (NB*NH)

#define QKV_ELEMS (NB*NH*NS*NDH)                 /* 4194304 */
#define ATTN_ELEMS ((size_t)NB*NH*(size_t)NS*NS) /* 33554432 */

typedef __bf16 bf16;
typedef __attribute__((ext_vector_type(8))) __bf16 bf16x8;
typedef __attribute__((ext_vector_type(4))) __bf16 bf16x4;
typedef __attribute__((ext_vector_type(4))) float f32x4;
typedef unsigned int u32;

// async global->LDS, 16B per lane. LDS dest must be WAVE-UNIFORM base; HW
// writes base + lane*16. Global src is per-lane. (m97 pattern, 874 TF.)
__device__ __forceinline__ void gload_lds16(const void* g, void* l) {
    __builtin_amdgcn_global_load_lds(
        (const __attribute__((address_space(1))) u32*)g,
        (__attribute__((address_space(3))) u32*)l, 16, 0, 0);
}

// XOR swizzle (short units): byte ^= ((row&7)<<4). Spreads power-of-2 row
// strides across banks; keeps 8-short (16B) groups contiguous (G4 recipe).
__device__ __forceinline__ int swz(int idx, int row) { return idx ^ ((row & 7) << 3); }

// ---------------------------------------------------------------------------
// K0: per-sample valid lengths (first zero index, else S). lens[0..7]=q, [8..15]=k
__global__ void lens_kernel(const int* __restrict__ pq, const int* __restrict__ pk,
                            int* __restrict__ lens) {
    int bi = blockIdx.x;
    const int* v = (bi < NB) ? pq : pk;
    int b = bi & (NB - 1);
    int lane = threadIdx.x;
    int local = NS;
#pragma unroll
    for (int p = 0; p < NS / 64; ++p) {
        int idx = p * 64 + lane;
        if (v[b * NS + idx] == 0 && idx < local) local = idx;
    }
#pragma unroll
    for (int m = 32; m >= 1; m >>= 1) {
        int o = __shfl_xor(local, m, 64);
        local = min(local, o);
    }
    if (lane == 0) lens[bi] = local;
}

// ---------------------------------------------------------------------------
// K1: convert hidden states fp32 [B,H,S,DH] -> bf16 A-matrix [m=b*S+s][c=h*64+d]
__global__ __launch_bounds__(256) void cvtA_kernel(
    const float* __restrict__ hl, const float* __restrict__ hc,
    bf16* __restrict__ al, bf16* __restrict__ ac) {
    const float* src = blockIdx.z ? hc : hl;
    bf16* dst = blockIdx.z ? ac : al;
    int tid = blockIdx.x * 256 + threadIdx.x;      // 524288 threads
    int d8 = tid & 7, s = (tid >> 3) & 511, h = (tid >> 12) & 15, b = tid >> 16;
    const float* p = &src[(((size_t)b * NH + h) * NS + s) * NDH + d8 * 8];
    float4 v0 = *(const float4*)p;
    float4 v1 = *(const float4*)(p + 4);
    bf16x8 o;
    o[0] = (bf16)v0.x; o[1] = (bf16)v0.y; o[2] = (bf16)v0.z; o[3] = (bf16)v0.w;
    o[4] = (bf16)v1.x; o[5] = (bf16)v1.y; o[6] = (bf16)v1.z; o[7] = (bf16)v1.w;
    *(bf16x8*)&dst[((size_t)(b * NS + s)) * NHID + h * NDH + d8 * 8] = o;
}

// ---------------------------------------------------------------------------
// K2: transpose weights fp32 [k][n] -> bf16 Wt[z][n][k]
__global__ __launch_bounds__(256) void cvtW_kernel(
    const float* __restrict__ Wq, const float* __restrict__ Wk,
    const float* __restrict__ Wv1, const float* __restrict__ Wv,
    bf16* __restrict__ Wt) {
    const float* W;
    switch (blockIdx.z) {
        case 0: W = Wq; break;
        case 1: W = Wk; break;
        case 2: W = Wv1; break;
        default: W = Wv; break;
    }
    bf16* out = Wt + (size_t)blockIdx.z * NHID * NHID;
    __shared__ bf16 T[64][72];
    int t = threadIdx.x;
    int k0 = blockIdx.y * 64, n0 = blockIdx.x * 64;
#pragma unroll
    for (int p = 0; p < 4; ++p) {
        int kk = p * 16 + (t >> 4), c4 = (t & 15) * 4;
        float4 v = *(const float4*)&W[(size_t)(k0 + kk) * NHID + n0 + c4];
        T[c4 + 0][kk] = (bf16)v.x;
        T[c4 + 1][kk] = (bf16)v.y;
        T[c4 + 2][kk] = (bf16)v.z;
        T[c4 + 3][kk] = (bf16)v.w;
    }
    __syncthreads();
#pragma unroll
    for (int p = 0; p < 2; ++p) {
        int f = p * 256 + t;
        int nn = f >> 3, k8 = (f & 7) * 8;
        bf16x8 o;
#pragma unroll
        for (int e = 0; e < 8; ++e) o[e] = T[nn][k8 + e];
        *(bf16x8*)&out[(size_t)(n0 + nn) * NHID + k0 + k8] = o;
    }
}

// ---------------------------------------------------------------------------
// K3: 4 projection GEMMs, bf16 MFMA, global_load_lds staging (m97 structure).
__global__ __launch_bounds__(256) void proj_kernel(
    const bf16* __restrict__ al, const bf16* __restrict__ ac,
    const bf16* __restrict__ Wt,
    const float* __restrict__ bq, const float* __restrict__ bk,
    const float* __restrict__ bv1, const float* __restrict__ bv,
    bf16* __restrict__ oq, bf16* __restrict__ ok,
    bf16* __restrict__ ov1, bf16* __restrict__ ovt) {
    __shared__ bf16 As[128 * 64];
    __shared__ bf16 Bs[128 * 64];
    const bf16* A; const bf16* W; const float* bias; bf16* dst;
    switch (blockIdx.z) {
        case 0: A = al; W = Wt;                 bias = bq;  dst = oq;  break;
        case 1: A = ac; W = Wt + 1048576;       bias = bk;  dst = ok;  break;
        case 2: A = al; W = Wt + 2097152;       bias = bv1; dst = ov1; break;
        default: A = ac; W = Wt + 3145728;      bias = bv;  dst = ovt; break;
    }
    int t = threadIdx.x, lane = t & 63, w = t >> 6;
    int wm = w & 1, wn = w >> 1;
    int m0 = blockIdx.y * 128, n0 = blockIdx.x * 128;
    int lrow = lane >> 3, lk8 = (lane & 7) * 8;
    f32x4 acc[4][4];
#pragma unroll
    for (int i = 0; i < 4; ++i)
#pragma unroll
        for (int j = 0; j < 4; ++j) acc[i][j] = (f32x4){0.f, 0.f, 0.f, 0.f};

    for (int kb = 0; kb < NHID; kb += 64) {
#pragma unroll
        for (int i = 0; i < 4; ++i) {
            int seg = w * 2048 + i * 512;              // elems; wave-uniform
            int row = (w * 32 + i * 8) + lrow;         // tile row this lane loads
            gload_lds16(&A[(size_t)(m0 + row) * NHID + kb + lk8], &As[seg]);
            gload_lds16(&W[(size_t)(n0 + row) * NHID + kb + lk8], &Bs[seg]);
        }
        __syncthreads();
#pragma unroll
        for (int ks = 0; ks < 2; ++ks) {
            int ko = ks * 32 + (lane >> 4) * 8;
            bf16x8 a[4], bb[4];
#pragma unroll
            for (int i = 0; i < 4; ++i)
                a[i] = *(const bf16x8*)&As[(wm * 64 + i * 16 + (lane & 15)) * 64 + ko];
#pragma unroll
            for (int j = 0; j < 4; ++j)
                bb[j] = *(const bf16x8*)&Bs[(wn * 64 + j * 16 + (lane & 15)) * 64 + ko];
#pragma unroll
            for (int i = 0; i < 4; ++i)
#pragma unroll
                for (int j = 0; j < 4; ++j)
                    acc[i][j] = __builtin_amdgcn_mfma_f32_16x16x32_bf16(a[i], bb[j], acc[i][j], 0, 0, 0);
        }
        __syncthreads();
    }
    float bsv[4];
#pragma unroll
    for (int j = 0; j < 4; ++j) bsv[j] = bias[n0 + wn * 64 + j * 16 + (lane & 15)];
#pragma unroll
    for (int i = 0; i < 4; ++i)
#pragma unroll
        for (int r = 0; r < 4; ++r) {
            int m = m0 + wm * 64 + i * 16 + (lane >> 4) * 4 + r;
            int b = m >> 9, s = m & (NS - 1);
#pragma unroll
            for (int j = 0; j < 4; ++j) {
                int n = n0 + wn * 64 + j * 16 + (lane & 15);
                dst[(((size_t)b * NH + (n >> 6)) * NS + s) * NDH + (n & 63)] =
                    (bf16)(acc[i][j][r] + bsv[j]);
            }
        }
}

// ---------------------------------------------------------------------------
// K4: fused scores + masked softmax + PV context. Per block: 32 ki x 512 qi.
// acc halved (64 f32/thread) vs old 64-ki version -> ~3 waves/SIMD occupancy.
__global__ __launch_bounds__(256) void attn_fused_kernel(
    const bf16* __restrict__ qb, const bf16* __restrict__ kb,
    const bf16* __restrict__ v1, const int* __restrict__ lens,
    float* __restrict__ scores, float* __restrict__ attn,
    float* __restrict__ ctx) {
    __shared__ bf16 Ks[32 * 64];        // 4 KB   [ki][d]
    __shared__ bf16 Ps[32 * 512];       // 32 KB  [ki][qi]  full P tile
    __shared__ bf16 Vs[64 * 128];       // 16 KB  [d][qc]   one 128-qi chunk
    __shared__ float redm[4][32];
    __shared__ float reds[4][32];
    int bh = blockIdx.y, ki0 = blockIdx.x * 32;
    int b = bh >> 4;
    int t = threadIdx.x, lane = t & 63, w = t >> 6;
    int lq = lens[b], lk = lens[NB + b];
    const bf16* kbb = kb + ((size_t)bh * NS + ki0) * NDH;
    const bf16* qbb = qb + (size_t)bh * NS * NDH;
    const bf16* vb  = v1 + (size_t)bh * NS * NDH;
    {   // K tile 32x64: one bf16x8 per thread
        int row = t >> 3, d8 = (t & 7) * 8;
        bf16x8 v = *(const bf16x8*)&kbb[(size_t)row * NDH + d8];
        *(bf16x8*)&Ks[swz(row * 64 + d8, row)] = v;
    }
    __syncthreads();
    f32x4 acc[2][8];
#pragma unroll
    for (int i = 0; i < 2; ++i)
#pragma unroll
        for (int j = 0; j < 8; ++j) acc[i][j] = (f32x4){0.f, 0.f, 0.f, 0.f};
#pragma unroll
    for (int ds = 0; ds < 2; ++ds) {
        int kofs = ds * 32 + (lane >> 4) * 8;
        bf16x8 a[2];
#pragma unroll
        for (int i = 0; i < 2; ++i) {
            int row = i * 16 + (lane & 15);
            a[i] = *(const bf16x8*)&Ks[swz(row * 64 + kofs, row)];
        }
        __builtin_amdgcn_s_setprio(1);
#pragma unroll
        for (int j = 0; j < 8; ++j) {
            int qi = w * 128 + j * 16 + (lane & 15);
            bf16x8 bq8 = *(const bf16x8*)&qbb[(size_t)qi * NDH + kofs];
#pragma unroll
            for (int i = 0; i < 2; ++i)
                acc[i][j] = __builtin_amdgcn_mfma_f32_16x16x32_bf16(a[i], bq8, acc[i][j], 0, 0, 0);
        }
        __builtin_amdgcn_s_setprio(0);
    }
    int g = lane >> 4, c = lane & 15;
    bool fullmask = (ki0 >= lq);
    // pass 1: scale + raw scores write (mandatory for ALL rows) + masked max
    float pmax[2][4];
#pragma unroll
    for (int i = 0; i < 2; ++i)
#pragma unroll
        for (int r = 0; r < 4; ++r) pmax[i][r] = -3.0e38f;
#pragma unroll
    for (int i = 0; i < 2; ++i)
#pragma unroll
        for (int j = 0; j < 8; ++j) {
            int qi = w * 128 + j * 16 + c;
            bool colv = qi < lk;
#pragma unroll
            for (int r = 0; r < 4; ++r) {
                float s = acc[i][j][r] * 0.125f;
                acc[i][j][r] = s;
                scores[((size_t)bh * NS + ki0 + i * 16 + g * 4 + r) * NS + qi] = s;
                if (colv) pmax[i][r] = fmaxf(pmax[i][r], s);
            }
        }
    if (fullmask) {                        // block-uniform: rows all masked
        float* ab = attn + ((size_t)bh * NS + ki0) * NS;   // 16384 f32
        float4 z = make_float4(0.f, 0.f, 0.f, 0.f);
#pragma unroll
        for (int p = 0; p < 16; ++p)
            *(float4*)&ab[(p * 256 + t) * 4] = z;
        float* cb = ctx + ((size_t)bh * NS + ki0) * NDH;   // 2048 f32
#pragma unroll
        for (int p = 0; p < 2; ++p)
            *(float4*)&cb[(p * 256 + t) * 4] = z;
        return;
    }
#pragma unroll
    for (int msk = 8; msk >= 1; msk >>= 1)
#pragma unroll
        for (int i = 0; i < 2; ++i)
#pragma unroll
            for (int r = 0; r < 4; ++r)
                pmax[i][r] = fmaxf(pmax[i][r], __shfl_xor(pmax[i][r], msk, 64));
    if (c == 0)
#pragma unroll
        for (int i = 0; i < 2; ++i)
#pragma unroll
            for (int r = 0; r < 4; ++r) redm[w][i * 16 + g * 4 + r] = pmax[i][r];
    __syncthreads();
    float rmax[2][4];
#pragma unroll
    for (int i = 0; i < 2; ++i)
#pragma unroll
        for (int r = 0; r < 4; ++r) {
            int row = i * 16 + g * 4 + r;
            rmax[i][r] = fmaxf(fmaxf(redm[0][row], redm[1][row]),
                               fmaxf(redm[2][row], redm[3][row]));
        }
    float psum[2][4];
#pragma unroll
    for (int i = 0; i < 2; ++i)
#pragma unroll
        for (int r = 0; r < 4; ++r) psum[i][r] = 0.f;
#pragma unroll
    for (int i = 0; i < 2; ++i)
#pragma unroll
        for (int j = 0; j < 8; ++j) {
            int qi = w * 128 + j * 16 + c;
            bool colv = qi < lk;
#pragma unroll
            for (int r = 0; r < 4; ++r) {
                float e = colv ? __expf(acc[i][j][r] - rmax[i][r]) : 0.f;
                acc[i][j][r] = e;
                psum[i][r] += e;
            }
        }
#pragma unroll
    for (int msk = 8; msk >= 1; msk >>= 1)
#pragma unroll
        for (int i = 0; i < 2; ++i)
#pragma unroll
            for (int r = 0; r < 4; ++r)
                psum[i][r] += __shfl_xor(psum[i][r], msk, 64);
    if (c == 0)
#pragma unroll
        for (int i = 0; i < 2; ++i)
#pragma unroll
            for (int r = 0; r < 4; ++r) reds[w][i * 16 + g * 4 + r] = psum[i][r];
    __syncthreads();
    // finalize P in-register, write attn, publish full P tile to LDS
#pragma unroll
    for (int i = 0; i < 2; ++i)
#pragma unroll
        for (int r = 0; r < 4; ++r) {
            int row = i * 16 + g * 4 + r;
            float rs = reds[0][row] + reds[1][row] + reds[2][row] + reds[3][row];
            float inv = (rs > 0.f) ? 1.f / rs : 0.f;
            bool rowv = (ki0 + row) < lq;
            float fin = rowv ? inv : 0.f;
#pragma unroll
            for (int j = 0; j < 8; ++j) {
                int qi = w * 128 + j * 16 + c;
                float v = acc[i][j][r] * fin;
                acc[i][j][r] = v;
                attn[((size_t)bh * NS + ki0 + row) * NS + qi] = v;
                Ps[swz(row * 512 + qi, row)] = (bf16)v;
            }
        }
    // --- PV: ctx[32 ki][64 d] = P @ v1, V chunked 128 qi at a time ---
    f32x4 cacc[2];
#pragma unroll
    for (int i = 0; i < 2; ++i) cacc[i] = (f32x4){0.f, 0.f, 0.f, 0.f};
    for (int cq = 0; cq < 4; ++cq) {
        if (cq * 128 >= lk) break;             // tail chunks: P == 0
        __syncthreads();                       // Vs free; (cq=0: P publish done)
#pragma unroll
        for (int p = 0; p < 4; ++p) {          // V chunk 128 qi x 64 d -> [d][qc]
            int f = p * 256 + t;
            int qr = f >> 3, d8 = (f & 7) * 8;
            bf16x8 v = *(const bf16x8*)&vb[(size_t)(cq * 128 + qr) * NDH + d8];
#pragma unroll
            for (int e = 0; e < 8; ++e)
                Vs[swz((d8 + e) * 128 + qr, d8 + e)] = v[e];
        }
        __syncthreads();
        __builtin_amdgcn_s_setprio(1);
#pragma unroll
        for (int ks = 0; ks < 4; ++ks) {       // K=128 per chunk
            int klo = ks * 32 + (lane >> 4) * 8;
            int d = w * 16 + (lane & 15);
            bf16x8 bv8 = *(const bf16x8*)&Vs[swz(d * 128 + klo, d)];
#pragma unroll
            for (int i = 0; i < 2; ++i) {
                int arow = i * 16 + (lane & 15);
                bf16x8 pa = *(const bf16x8*)&Ps[swz(arow * 512 + cq * 128 + klo, arow)];
                cacc[i] = __builtin_amdgcn_mfma_f32_16x16x32_bf16(pa, bv8, cacc[i], 0, 0, 0);
            }
        }
        __builtin_amdgcn_s_setprio(0);
    }
#pragma unroll
    for (int i = 0; i < 2; ++i)
#pragma unroll
        for (int r = 0; r < 4; ++r) {
            int ki = ki0 + i * 16 + g * 4 + r;
            ctx[((size_t)bh * NS + ki) * NDH + w * 16 + c] = cacc[i][r];
        }
}

// ---------------------------------------------------------------------------
// K5: context2 = concat([ctx, vt], -1) @ W_cat + b_cat  (fp32, small)
__global__ __launch_bounds__(256) void cat_kernel(
    const float* __restrict__ ctx, const bf16* __restrict__ vt,
    const float* __restrict__ Wcat, const float* __restrict__ bcat,
    float* __restrict__ out) {
    __shared__ float As[16][68];
    __shared__ float Bs[16][68];
    int t = threadIdx.x;
    int tx = t & 15, ty = t >> 4;
    int row0 = blockIdx.x * 64;
    float acc[4][4];
#pragma unroll
    for (int i = 0; i < 4; ++i)
#pragma unroll
        for (int j = 0; j < 4; ++j) acc[i][j] = 0.f;

    for (int k0 = 0; k0 < 2 * NDH; k0 += 16) {
#pragma unroll
        for (int p = 0; p < 4; ++p) {
            int e = p * 256 + t;
            int kk = e & 15, mm = e >> 4;
            int cidx = k0 + kk;
            float val = (cidx < NDH) ? ctx[(size_t)(row0 + mm) * NDH + cidx]
                                     : (float)vt[(size_t)(row0 + mm) * NDH + (cidx - NDH)];
            As[kk][mm] = val;
        }
#pragma unroll
        for (int p = 0; p < 4; ++p) {
            int e = p * 256 + t;
            int nn = e & 63, kk = e >> 6;
            Bs[kk][nn] = Wcat[(size_t)(k0 + kk) * NDH + nn];
        }
        __syncthreads();
#pragma unroll
        for (int kk = 0; kk < 16; ++kk) {
            float a[4], bb[4];
            *(float4*)&a[0]  = *(const float4*)&As[kk][ty * 4];
            *(float4*)&bb[0] = *(const float4*)&Bs[kk][tx * 4];
#pragma unroll
            for (int i = 0; i < 4; ++i)
#pragma unroll
                for (int j = 0; j < 4; ++j) acc[i][j] += a[i] * bb[j];
        }
        __syncthreads();
    }
#pragma unroll
    for (int i = 0; i < 4; ++i) {
        int n = tx * 4;
        float4 o;
        o.x = acc[i][0] + bcat[n + 0];
        o.y = acc[i][1] + bcat[n + 1];
        o.z = acc[i][2] + bcat[n + 2];
        o.w = acc[i][3] + bcat[n + 3];
        *(float4*)&out[(size_t)(row0 + ty * 4 + i) * NDH + n] = o;
    }
}

// ---------------------------------------------------------------------------
extern "C" void kernel_launch(void* const* d_in, const int* in_sizes, int n_in,
                              void* d_out, int out_size, void* d_ws, size_t ws_size,
                              hipStream_t stream) {
    (void)in_sizes; (void)n_in; (void)out_size; (void)ws_size;
    const int*   pq   = (const int*)d_in[0];
    const int*   pk   = (const int*)d_in[1];
    const float* hl   = (const float*)d_in[6];
    const float* hc   = (const float*)d_in[7];
    const float* Wv1  = (const float*)d_in[11];
    const float* bv1  = (const float*)d_in[12];
    const float* Wv   = (const float*)d_in[13];
    const float* bv   = (const float*)d_in[14];
    const float* Wq   = (const float*)d_in[15];
    const float* bq   = (const float*)d_in[16];
    const float* Wk   = (const float*)d_in[17];
    const float* bk   = (const float*)d_in[18];
    const float* Wcat = (const float*)d_in[19];
    const float* bcat = (const float*)d_in[20];

    float* out_attn   = (float*)d_out;             // [B,H,S,S]
    float* out_scores = out_attn + ATTN_ELEMS;     // [B,H,S,S]
    float* out_ctx2   = out_attn + 2 * ATTN_ELEMS; // [B,H,S,DH]
    float* out_ctx    = out_ctx2 + QKV_ELEMS;      // [B,H,S,DH]

    // ws layout (bytes): all bf16 intermediates live in workspace (~58.7 MB).
    char* ws = (char*)d_ws;
    bf16* al   = (bf16*)(ws);                        // A_last  [4096][1024]
    bf16* acb  = (bf16*)(ws + 8388608);              // A_cur
    bf16* WtB  = (bf16*)(ws + 16777216);             // Wt [4][1024][1024]
    bf16* qb   = (bf16*)(ws + 25165824);
    bf16* kbp  = (bf16*)(ws + 33554432);
    bf16* v1b  = (bf16*)(ws + 41943040);
    bf16* vtb  = (bf16*)(ws + 50331648);
    int*  lens = (int*)(ws + 58720256);

    lens_kernel<<<16, 64, 0, stream>>>(pq, pk, lens);
    cvtA_kernel<<<dim3(2048, 1, 2), 256, 0, stream>>>(hl, hc, al, acb);
    cvtW_kernel<<<dim3(16, 16, 4), 256, 0, stream>>>(Wq, Wk, Wv1, Wv, WtB);
    proj_kernel<<<dim3(8, 32, 4), 256, 0, stream>>>(
        al, acb, WtB, bq, bk, bv1, bv, qb, kbp, v1b, vtb);
    attn_fused_kernel<<<dim3(16, NBH), 256, 0, stream>>>(
        qb, kbp, v1b, lens, out_scores, out_attn, out_ctx);
    cat_kernel<<<(NB * NH * NS) / 64, 256, 0, stream>>>(out_ctx, vtb, Wcat, bcat, out_ctx2);
}